// Round 1
// baseline (1571.098 us; speedup 1.0000x reference)
//
#include <hip/hip_runtime.h>
#include <math.h>

#define B_ 8192
#define NN 32
#define TD 100
#define MD 172
#define KD 1376   // MD*8
#define TAUC 0.3f
#define LAMC 0.01f

__device__ __forceinline__ float wred(float v) {
#pragma unroll
  for (int o = 32; o > 0; o >>= 1) v += __shfl_down(v, o, 64);
  return v;
}

// ---- Kernel 1: global energy mean via Parseval: sum over (b,n,c) of tfeat^2 ----
__global__ __launch_bounds__(256) void k_mean(const int* __restrict__ nid,
                                              const float* __restrict__ t,
                                              const float* __restrict__ nt,
                                              float* __restrict__ ws) {
  __shared__ float fr[TD];
  __shared__ float part[4];
  int tid = threadIdx.x;
  if (tid < TD) fr[tid] = (float)exp(-9.0 * (double)tid / 99.0 * 2.302585092994045684);
  __syncthreads();
  int idx = blockIdx.x * 256 + tid;   // 0..262143 exactly (1024 blocks)
  int b = idx >> 5;
  float s = 0.f;
  if (nid[idx] != 0) {
    float dt = t[b] - nt[idx];
    for (int c = 0; c < TD; ++c) { float v = cosf(dt * fr[c]); s = fmaf(v, v, s); }
  }
  s = wred(s);
  if ((tid & 63) == 0) part[tid >> 6] = s;
  __syncthreads();
  if (tid == 0) atomicAdd(ws, part[0] + part[1] + part[2] + part[3]);
}

// ---- Kernel 2: per-b fused pipeline ----
__global__ __launch_bounds__(384) void k_main(
    const int* __restrict__ node_ids, const int* __restrict__ nbr_id,
    const float* __restrict__ t, const float* __restrict__ nt,
    const float* __restrict__ node_mem,
    const float* __restrict__ r1, const float* __restrict__ i1,
    const float* __restrict__ rb1, const float* __restrict__ ib1,
    const float* __restrict__ conv_w, const float* __restrict__ conv_b,
    const float* __restrict__ rhythm_w, const float* __restrict__ lin_w,
    const float* __restrict__ lin_b, const float* __restrict__ mb_w,
    const float* __restrict__ mb_b, const float* __restrict__ ln_w,
    const float* __restrict__ ln_b, const float* __restrict__ ws0,
    float* __restrict__ u_out, float* __restrict__ out, int fused) {
  __shared__ __align__(16) float sp[5504];          // tfeat (3200) then u-partials (4*1376)
  __shared__ __align__(16) float sxr[3200];
  __shared__ __align__(16) float sxi[3200];
  __shared__ float s_fr[TD];
  __shared__ float s_c32[32], s_s32[32], s_dt[32], s_z[32], s_msk[32];
  __shared__ float s_Ct[256], s_St[256];
  __shared__ float s_red[16];

  const int tid = threadIdx.x;
  const int b = blockIdx.x;
  const float inv_s = 0.17677669529663687f;  // 1/sqrt(32)

  // phase 1: twiddles, dt, freqs
  if (tid < 32) {
    double ang = 0.19634954084936207740 * (double)tid;  // 2*pi/32
    s_c32[tid] = (float)cos(ang);
    s_s32[tid] = (float)sin(ang);
    int gi = b * NN + tid;
    int id = nbr_id[gi];
    float d = t[b] - nt[gi];
    s_z[tid]  = (id == 0) ? 0.f : 1.f;
    s_dt[tid] = (id == 0) ? 0.f : d;
  }
  if (tid < TD) s_fr[tid] = (float)exp(-9.0 * (double)tid / 99.0 * 2.302585092994045684);
  __syncthreads();

  // phase 2: tfeat into sp; Ct/St tables (ifft folded with conv-window sums)
  for (int idx = tid; idx < NN * TD; idx += 384) {
    int n = idx / TD, c = idx - n * TD;
    sp[idx] = s_z[n] * cosf(s_dt[n] * s_fr[c]);
  }
  if (tid < 256) {
    int k2 = tid >> 5, kp = tid & 31;
    int lo = k2 - 4; if (lo < 0) lo = 0;
    int hi = k2 + 28; if (hi > 31) hi = 31;
    float cs = 0.f, ss = 0.f;
    for (int n = lo; n <= hi; ++n) {
      int j = (kp * n) & 31;
      cs += s_c32[j]; ss += s_s32[j];
    }
    s_Ct[tid] = cs * inv_s;
    s_St[tid] = ss * inv_s;
  }
  __syncthreads();

  // phase 3: DFT over n (k=0..16, mirror 17..31), c in float4 groups
  for (int task = tid; task < 17 * 25; task += 384) {
    int k = task / 25, c4 = (task - k * 25) * 4;
    float ar0=0,ar1=0,ar2=0,ar3=0, ai0=0,ai1=0,ai2=0,ai3=0;
    for (int n = 0; n < NN; ++n) {
      float4 a = *(const float4*)(sp + n * TD + c4);
      int j = (k * n) & 31;
      float cw = s_c32[j], sw = s_s32[j];
      ar0 = fmaf(a.x, cw, ar0); ai0 = fmaf(a.x, -sw, ai0);
      ar1 = fmaf(a.y, cw, ar1); ai1 = fmaf(a.y, -sw, ai1);
      ar2 = fmaf(a.z, cw, ar2); ai2 = fmaf(a.z, -sw, ai2);
      ar3 = fmaf(a.w, cw, ar3); ai3 = fmaf(a.w, -sw, ai3);
    }
    float4 vr = make_float4(ar0*inv_s, ar1*inv_s, ar2*inv_s, ar3*inv_s);
    float4 vi = make_float4(ai0*inv_s, ai1*inv_s, ai2*inv_s, ai3*inv_s);
    *(float4*)(sxr + k * TD + c4) = vr;
    *(float4*)(sxi + k * TD + c4) = vi;
    if (k >= 1 && k <= 15) {
      *(float4*)(sxr + (32 - k) * TD + c4) = vr;
      *(float4*)(sxi + (32 - k) * TD + c4) = make_float4(-vi.x, -vi.y, -vi.z, -vi.w);
    }
  }
  __syncthreads();

  // phase 4: per-k energy + mask vs global mean
  if (tid < 32) {
    float e = 0.f;
    for (int c4 = 0; c4 < TD; c4 += 4) {
      float4 a  = *(const float4*)(sxr + tid * TD + c4);
      float4 bb = *(const float4*)(sxi + tid * TD + c4);
      e += a.x*a.x + a.y*a.y + a.z*a.z + a.w*a.w;
      e += bb.x*bb.x + bb.y*bb.y + bb.z*bb.z + bb.w*bb.w;
    }
    float mean = ws0[0] * (1.0f / 262144.0f);
    s_msk[tid] = (e >= TAUC * (mean + 1e-6f)) ? 1.f : 0.f;
  }
  __syncthreads();

  // phase 5: apply mask
  for (int v = tid; v < 800; v += 384) {
    float m = s_msk[v / 25];
    float4* pr = ((float4*)sxr) + v;
    float4* pi = ((float4*)sxi) + v;
    float4 a = *pr, bb = *pi;
    *pr = make_float4(a.x*m, a.y*m, a.z*m, a.w*m);
    *pi = make_float4(bb.x*m, bb.y*m, bb.z*m, bb.w*m);
  }
  __syncthreads();

  // phase 6: complex GEMM [32,100]@[100,172] + bias + relu/softshrink + u-partials
  if (tid < 344) {
    int kg = tid / 86, dp = tid - (tid / 86) * 86;
    int d0 = dp * 2;
    float oR0[8], oI0[8], oR1[8], oI1[8];
#pragma unroll
    for (int j = 0; j < 8; ++j) { oR0[j]=0;oI0[j]=0;oR1[j]=0;oI1[j]=0; }
    const float* xrp = sxr + kg * 8 * TD;
    const float* xip = sxi + kg * 8 * TD;
    for (int c4 = 0; c4 < TD; c4 += 4) {
      float2 wr[4], wi[4];
#pragma unroll
      for (int q = 0; q < 4; ++q) {
        wr[q] = *(const float2*)(r1 + (c4 + q) * MD + d0);
        wi[q] = *(const float2*)(i1 + (c4 + q) * MD + d0);
      }
#pragma unroll
      for (int j = 0; j < 8; ++j) {
        float4 a4 = *(const float4*)(xrp + j * TD + c4);
        float4 b4 = *(const float4*)(xip + j * TD + c4);
        float xa[4] = {a4.x, a4.y, a4.z, a4.w};
        float xb[4] = {b4.x, b4.y, b4.z, b4.w};
#pragma unroll
        for (int q = 0; q < 4; ++q) {
          oR0[j] = fmaf(xa[q],  wr[q].x, oR0[j]);
          oR0[j] = fmaf(xb[q], -wi[q].x, oR0[j]);
          oI0[j] = fmaf(xb[q],  wr[q].x, oI0[j]);
          oI0[j] = fmaf(xa[q],  wi[q].x, oI0[j]);
          oR1[j] = fmaf(xa[q],  wr[q].y, oR1[j]);
          oR1[j] = fmaf(xb[q], -wi[q].y, oR1[j]);
          oI1[j] = fmaf(xb[q],  wr[q].y, oI1[j]);
          oI1[j] = fmaf(xa[q],  wi[q].y, oI1[j]);
        }
      }
    }
    float2 rb = *(const float2*)(rb1 + d0);
    float2 ib = *(const float2*)(ib1 + d0);
    float upA[8], upB[8];
#pragma unroll
    for (int k2 = 0; k2 < 8; ++k2) { upA[k2]=0; upB[k2]=0; }
#pragma unroll
    for (int j = 0; j < 8; ++j) {
      int kp = kg * 8 + j;
      // softshrink(relu(x)) == max(x - lam, 0)
      float yr0 = fmaxf(oR0[j] + rb.x - LAMC, 0.f);
      float yi0 = fmaxf(oI0[j] + ib.x - LAMC, 0.f);
      float yr1 = fmaxf(oR1[j] + rb.y - LAMC, 0.f);
      float yi1 = fmaxf(oI1[j] + ib.y - LAMC, 0.f);
#pragma unroll
      for (int k2 = 0; k2 < 8; ++k2) {
        float Cv = s_Ct[k2 * 32 + kp], Sv = s_St[k2 * 32 + kp];
        upA[k2] = fmaf(yr0, Cv, upA[k2]); upA[k2] = fmaf(yi0, -Sv, upA[k2]);
        upB[k2] = fmaf(yr1, Cv, upB[k2]); upB[k2] = fmaf(yi1, -Sv, upB[k2]);
      }
    }
#pragma unroll
    for (int k2 = 0; k2 < 8; ++k2) {
      *(float2*)(sp + kg * KD + k2 * MD + d0) = make_float2(upA[k2], upB[k2]);
    }
  }
  __syncthreads();

  // phase 7: reduce u over the 4 kg partials; write u (natural conv_w order kappa=i*8+k2)
  if (fused == 0) {
    for (int kk = tid; kk < KD; kk += 384) {
      int i = kk >> 3, k2 = kk & 7;
      int o_ = k2 * MD + i;
      u_out[(long)b * KD + kk] = sp[o_] + sp[KD + o_] + sp[2*KD + o_] + sp[3*KD + o_];
    }
  } else {
    for (int kk = tid; kk < KD; kk += 384) {
      int i = kk >> 3, k2 = kk & 7;
      int o_ = k2 * MD + i;
      sxr[kk] = sp[o_] + sp[KD + o_] + sp[2*KD + o_] + sp[3*KD + o_];
    }
    __syncthreads();
    int w = tid >> 6, lane = tid & 63;
    for (int o = w; o < MD; o += 6) {
      float p = 0.f;
      for (int kq = lane; kq < KD; kq += 64)
        p = fmaf(sxr[kq], conv_w[o * KD + kq], p);
      p = wred(p);
      if (lane == 0) sxi[1400 + o] = p * (1.0f / 33.0f) + conv_b[o];
    }
  }
  __syncthreads();

  // phase 8: root branch (rhythm conv collapsed) + two LayerNorms
  float* s_g  = sxi;          // 272
  float* s_nm = sxi + 288;    // 172
  for (int c = tid; c < 272; c += 384) {
    float m;
    if (c < TD) m = cosf(t[b] * s_fr[c]);
    else        m = node_mem[(long)node_ids[b] * MD + (c - TD)];
    float hw = 0.5f * (rhythm_w[c * 4 + 1] + rhythm_w[c * 4 + 2]);
    s_g[c] = m * hw;
  }
  __syncthreads();
  if (tid < MD) {
    float acc = 0.f;
    for (int c = 0; c < 272; ++c) acc = fmaf(s_g[c], lin_w[c * MD + tid], acc);
    s_nm[tid] = acc + lin_b[tid];
  }
  __syncthreads();
  float v = (tid < MD) ? s_nm[tid] : 0.f;
  float s1 = wred(v), s2 = wred(v * v);
  if ((tid & 63) == 0) { s_red[tid >> 6] = s1; s_red[8 + (tid >> 6)] = s2; }
  __syncthreads();
  if (tid == 0) {
    float a = 0, q = 0;
    for (int wv = 0; wv < 6; ++wv) { a += s_red[wv]; q += s_red[8 + wv]; }
    float mean = a / 172.0f;
    float var  = q / 172.0f - mean * mean;
    s_red[14] = mean; s_red[15] = rsqrtf(var + 1e-5f);
  }
  __syncthreads();
  float h = 0.f;
  if (tid < MD) h = (v - s_red[14]) * s_red[15] * mb_w[tid] + mb_b[tid];
  __syncthreads();
  float t1 = wred((tid < MD) ? h : 0.f), t2 = wred((tid < MD) ? h * h : 0.f);
  if ((tid & 63) == 0) { s_red[tid >> 6] = t1; s_red[8 + (tid >> 6)] = t2; }
  __syncthreads();
  if (tid == 0) {
    float a = 0, q = 0;
    for (int wv = 0; wv < 6; ++wv) { a += s_red[wv]; q += s_red[8 + wv]; }
    float mean = a / 172.0f;
    float var  = q / 172.0f - mean * mean;
    s_red[14] = mean; s_red[15] = rsqrtf(var + 1e-5f);
  }
  __syncthreads();
  if (tid < MD) {
    float ov = (h - s_red[14]) * s_red[15] * ln_w[tid] + ln_b[tid];
    out[(long)b * MD + tid] = ov + (fused ? sxi[1400 + tid] : 0.f);
  }
}

// ---- Kernel 3: out[b,o] += (1/33) * u[b,:] . conv_w[o,:] + conv_b[o] ----
__global__ __launch_bounds__(256) void k_conv(const float* __restrict__ u,
                                              const float* __restrict__ conv_w,
                                              const float* __restrict__ conv_b,
                                              float* __restrict__ out) {
  __shared__ float Wl[32 * 173 + 16];
  __shared__ float Ul[16 * 33];
  const int tid = threadIdx.x;
  const int b0 = blockIdx.x * 16;
  const int r_ = tid >> 4, oc = tid & 15;
  float acc[11];
#pragma unroll
  for (int j = 0; j < 11; ++j) acc[j] = 0.f;
  for (int ch = 0; ch < 43; ++ch) {
    const int k0 = ch * 32;
    __syncthreads();
    for (int e = tid; e < 32 * MD; e += 256) {
      int o = e >> 5, j = e & 31;
      Wl[j * 173 + o] = conv_w[o * KD + k0 + j];
    }
    for (int e = tid; e < 512; e += 256) {
      int rr = e >> 5, j = e & 31;
      Ul[rr * 33 + j] = u[(long)(b0 + rr) * KD + k0 + j];
    }
    __syncthreads();
    for (int jj = 0; jj < 32; ++jj) {
      float uv = Ul[r_ * 33 + jj];
#pragma unroll
      for (int j = 0; j < 11; ++j) {
        acc[j] = fmaf(uv, Wl[jj * 173 + oc + 16 * j], acc[j]);
      }
    }
  }
#pragma unroll
  for (int j = 0; j < 11; ++j) {
    int o = oc + 16 * j;
    if (o < MD) {
      long oi = (long)(b0 + r_) * MD + o;
      out[oi] += acc[j] * (1.0f / 33.0f) + conv_b[o];
    }
  }
}

extern "C" void kernel_launch(void* const* d_in, const int* in_sizes, int n_in,
                              void* d_out, int out_size, void* d_ws, size_t ws_size,
                              hipStream_t stream) {
  const int* node_ids = (const int*)d_in[0];
  const int* nbr_id   = (const int*)d_in[1];
  const float* t  = (const float*)d_in[2];
  const float* nt = (const float*)d_in[3];
  const float* node_mem = (const float*)d_in[4];
  const float* r1 = (const float*)d_in[5];
  const float* i1 = (const float*)d_in[6];
  const float* rb1 = (const float*)d_in[7];
  const float* ib1 = (const float*)d_in[8];
  const float* conv_w = (const float*)d_in[9];
  const float* conv_b = (const float*)d_in[10];
  const float* rhythm_w = (const float*)d_in[11];
  const float* lin_w = (const float*)d_in[12];
  const float* lin_b = (const float*)d_in[13];
  const float* mb_w = (const float*)d_in[14];
  const float* mb_b = (const float*)d_in[15];
  const float* ln_w = (const float*)d_in[16];
  const float* ln_b = (const float*)d_in[17];
  float* out = (float*)d_out;
  float* wsf = (float*)d_ws;
  size_t need = 256 + (size_t)B_ * KD * sizeof(float);
  int fused = (ws_size >= need) ? 0 : 1;   // fused==1: no workspace GEMM, do conv in k_main
  float* u = wsf + 64;
  hipMemsetAsync(d_ws, 0, 16, stream);
  k_mean<<<1024, 256, 0, stream>>>(nbr_id, t, nt, wsf);
  k_main<<<B_, 384, 0, stream>>>(node_ids, nbr_id, t, nt, node_mem, r1, i1,
                                 rb1, ib1, conv_w, conv_b, rhythm_w, lin_w,
                                 lin_b, mb_w, mb_b, ln_w, ln_b, wsf, u, out, fused);
  if (!fused)
    k_conv<<<512, 256, 0, stream>>>(u, conv_w, conv_b, out);
}

// Round 2
// 1273.999 us; speedup vs baseline: 1.2332x; 1.2332x over previous
//
#include <hip/hip_runtime.h>
#include <hip/hip_bf16.h>
#include <math.h>

#define B_ 8192
#define NN 32
#define TD 100
#define MD 172
#define KD 1376   // MD*8
#define TAUC 0.3f
#define LAMC 0.01f

typedef __attribute__((ext_vector_type(8))) short short8;
typedef __attribute__((ext_vector_type(4))) float f32x4;

__device__ __forceinline__ float wred(float v) {
#pragma unroll
  for (int o = 32; o > 0; o >>= 1) v += __shfl_down(v, o, 64);
  return v;
}

__device__ __forceinline__ short bf16_bits(float f) {
  __hip_bfloat16 h = __float2bfloat16(f);
  return *(short*)&h;
}

// ---- Kernel 1: global energy mean via Parseval: sum over (b,n,c) of tfeat^2 ----
__global__ __launch_bounds__(256) void k_mean(const int* __restrict__ nid,
                                              const float* __restrict__ t,
                                              const float* __restrict__ nt,
                                              float* __restrict__ ws) {
  __shared__ float fr[TD];
  __shared__ float part[4];
  int tid = threadIdx.x;
  if (tid < TD) fr[tid] = (float)exp(-9.0 * (double)tid / 99.0 * 2.302585092994045684);
  __syncthreads();
  int idx = blockIdx.x * 256 + tid;   // 0..262143 exactly (1024 blocks)
  int b = idx >> 5;
  float s = 0.f;
  if (nid[idx] != 0) {
    float dt = t[b] - nt[idx];
    for (int c = 0; c < TD; ++c) { float v = cosf(dt * fr[c]); s = fmaf(v, v, s); }
  }
  s = wred(s);
  if ((tid & 63) == 0) part[tid >> 6] = s;
  __syncthreads();
  if (tid == 0) atomicAdd(ws, part[0] + part[1] + part[2] + part[3]);
}

// ---- Kernel 1b: conv_w^T -> bf16 B-fragment layout for 16x16x32 MFMA ----
// Bfrag linear index: (((n0*43 + s)*64 + lane)*8 + j)
//   holds W2[k = s*32 + (lane>>4)*8 + j][col = n0*16 + (lane&15)], W2[k][o]=conv_w[o*KD+k]
__global__ __launch_bounds__(256) void k_prep(const float* __restrict__ conv_w,
                                              short* __restrict__ Bfrag) {
  int idx = blockIdx.x * 256 + threadIdx.x;
  if (idx >= 11 * 43 * 64 * 8) return;
  int j = idx & 7;
  int l = (idx >> 3) & 63;
  int s = (idx >> 9) % 43;
  int n0 = idx / (43 * 64 * 8);
  int k = s * 32 + (l >> 4) * 8 + j;
  int col = n0 * 16 + (l & 15);
  float v = (col < MD) ? conv_w[(long)col * KD + k] : 0.f;
  Bfrag[idx] = bf16_bits(v);
}

// ---- Kernel 2: per-b fused pipeline ----
__global__ __launch_bounds__(384) void k_main(
    const int* __restrict__ node_ids, const int* __restrict__ nbr_id,
    const float* __restrict__ t, const float* __restrict__ nt,
    const float* __restrict__ node_mem,
    const float* __restrict__ r1, const float* __restrict__ i1,
    const float* __restrict__ rb1, const float* __restrict__ ib1,
    const float* __restrict__ conv_w, const float* __restrict__ conv_b,
    const float* __restrict__ rhythm_w, const float* __restrict__ lin_w,
    const float* __restrict__ lin_b, const float* __restrict__ mb_w,
    const float* __restrict__ mb_b, const float* __restrict__ ln_w,
    const float* __restrict__ ln_b, const float* __restrict__ ws0,
    short* __restrict__ u_out, float* __restrict__ out, int fused) {
  __shared__ __align__(16) float sp[5504];          // tfeat (3200) then u-partials (4*1376)
  __shared__ __align__(16) float sxr[3200];
  __shared__ __align__(16) float sxi[3200];
  __shared__ float s_fr[TD];
  __shared__ float s_c32[32], s_s32[32], s_dt[32], s_z[32], s_msk[32];
  __shared__ float s_Ct[256], s_St[256];
  __shared__ float s_red[16];

  const int tid = threadIdx.x;
  const int b = blockIdx.x;
  const float inv_s = 0.17677669529663687f;  // 1/sqrt(32)

  // phase 1: twiddles, dt, freqs
  if (tid < 32) {
    double ang = 0.19634954084936207740 * (double)tid;  // 2*pi/32
    s_c32[tid] = (float)cos(ang);
    s_s32[tid] = (float)sin(ang);
    int gi = b * NN + tid;
    int id = nbr_id[gi];
    float d = t[b] - nt[gi];
    s_z[tid]  = (id == 0) ? 0.f : 1.f;
    s_dt[tid] = (id == 0) ? 0.f : d;
  }
  if (tid < TD) s_fr[tid] = (float)exp(-9.0 * (double)tid / 99.0 * 2.302585092994045684);
  __syncthreads();

  // phase 2: tfeat into sp; Ct/St tables (ifft folded with conv-window sums)
  for (int idx = tid; idx < NN * TD; idx += 384) {
    int n = idx / TD, c = idx - n * TD;
    sp[idx] = s_z[n] * cosf(s_dt[n] * s_fr[c]);
  }
  if (tid < 256) {
    int k2 = tid >> 5, kp = tid & 31;
    int lo = k2 - 4; if (lo < 0) lo = 0;
    int hi = k2 + 28; if (hi > 31) hi = 31;
    float cs = 0.f, ss = 0.f;
    for (int n = lo; n <= hi; ++n) {
      int j = (kp * n) & 31;
      cs += s_c32[j]; ss += s_s32[j];
    }
    s_Ct[tid] = cs * inv_s;
    s_St[tid] = ss * inv_s;
  }
  __syncthreads();

  // phase 3: DFT over n (k=0..16, mirror 17..31), c in float4 groups
  for (int task = tid; task < 17 * 25; task += 384) {
    int k = task / 25, c4 = (task - k * 25) * 4;
    float ar0=0,ar1=0,ar2=0,ar3=0, ai0=0,ai1=0,ai2=0,ai3=0;
    for (int n = 0; n < NN; ++n) {
      float4 a = *(const float4*)(sp + n * TD + c4);
      int j = (k * n) & 31;
      float cw = s_c32[j], sw = s_s32[j];
      ar0 = fmaf(a.x, cw, ar0); ai0 = fmaf(a.x, -sw, ai0);
      ar1 = fmaf(a.y, cw, ar1); ai1 = fmaf(a.y, -sw, ai1);
      ar2 = fmaf(a.z, cw, ar2); ai2 = fmaf(a.z, -sw, ai2);
      ar3 = fmaf(a.w, cw, ar3); ai3 = fmaf(a.w, -sw, ai3);
    }
    float4 vr = make_float4(ar0*inv_s, ar1*inv_s, ar2*inv_s, ar3*inv_s);
    float4 vi = make_float4(ai0*inv_s, ai1*inv_s, ai2*inv_s, ai3*inv_s);
    *(float4*)(sxr + k * TD + c4) = vr;
    *(float4*)(sxi + k * TD + c4) = vi;
    if (k >= 1 && k <= 15) {
      *(float4*)(sxr + (32 - k) * TD + c4) = vr;
      *(float4*)(sxi + (32 - k) * TD + c4) = make_float4(-vi.x, -vi.y, -vi.z, -vi.w);
    }
  }
  __syncthreads();

  // phase 4: per-k energy + mask vs global mean
  if (tid < 32) {
    float e = 0.f;
    for (int c4 = 0; c4 < TD; c4 += 4) {
      float4 a  = *(const float4*)(sxr + tid * TD + c4);
      float4 bb = *(const float4*)(sxi + tid * TD + c4);
      e += a.x*a.x + a.y*a.y + a.z*a.z + a.w*a.w;
      e += bb.x*bb.x + bb.y*bb.y + bb.z*bb.z + bb.w*bb.w;
    }
    float mean = ws0[0] * (1.0f / 262144.0f);
    s_msk[tid] = (e >= TAUC * (mean + 1e-6f)) ? 1.f : 0.f;
  }
  __syncthreads();

  // phase 5: apply mask
  for (int v = tid; v < 800; v += 384) {
    float m = s_msk[v / 25];
    float4* pr = ((float4*)sxr) + v;
    float4* pi = ((float4*)sxi) + v;
    float4 a = *pr, bb = *pi;
    *pr = make_float4(a.x*m, a.y*m, a.z*m, a.w*m);
    *pi = make_float4(bb.x*m, bb.y*m, bb.z*m, bb.w*m);
  }
  __syncthreads();

  // phase 6: complex GEMM [32,100]@[100,172] + bias + relu/softshrink + u-partials
  if (tid < 344) {
    int kg = tid / 86, dp = tid - (tid / 86) * 86;
    int d0 = dp * 2;
    float oR0[8], oI0[8], oR1[8], oI1[8];
#pragma unroll
    for (int j = 0; j < 8; ++j) { oR0[j]=0;oI0[j]=0;oR1[j]=0;oI1[j]=0; }
    const float* xrp = sxr + kg * 8 * TD;
    const float* xip = sxi + kg * 8 * TD;
    for (int c4 = 0; c4 < TD; c4 += 4) {
      float2 wr[4], wi[4];
#pragma unroll
      for (int q = 0; q < 4; ++q) {
        wr[q] = *(const float2*)(r1 + (c4 + q) * MD + d0);
        wi[q] = *(const float2*)(i1 + (c4 + q) * MD + d0);
      }
#pragma unroll
      for (int j = 0; j < 8; ++j) {
        float4 a4 = *(const float4*)(xrp + j * TD + c4);
        float4 b4 = *(const float4*)(xip + j * TD + c4);
        float xa[4] = {a4.x, a4.y, a4.z, a4.w};
        float xb[4] = {b4.x, b4.y, b4.z, b4.w};
#pragma unroll
        for (int q = 0; q < 4; ++q) {
          oR0[j] = fmaf(xa[q],  wr[q].x, oR0[j]);
          oR0[j] = fmaf(xb[q], -wi[q].x, oR0[j]);
          oI0[j] = fmaf(xb[q],  wr[q].x, oI0[j]);
          oI0[j] = fmaf(xa[q],  wi[q].x, oI0[j]);
          oR1[j] = fmaf(xa[q],  wr[q].y, oR1[j]);
          oR1[j] = fmaf(xb[q], -wi[q].y, oR1[j]);
          oI1[j] = fmaf(xb[q],  wr[q].y, oI1[j]);
          oI1[j] = fmaf(xa[q],  wi[q].y, oI1[j]);
        }
      }
    }
    float2 rb = *(const float2*)(rb1 + d0);
    float2 ib = *(const float2*)(ib1 + d0);
    float upA[8], upB[8];
#pragma unroll
    for (int k2 = 0; k2 < 8; ++k2) { upA[k2]=0; upB[k2]=0; }
#pragma unroll
    for (int j = 0; j < 8; ++j) {
      int kp = kg * 8 + j;
      // softshrink(relu(x)) == max(x - lam, 0)
      float yr0 = fmaxf(oR0[j] + rb.x - LAMC, 0.f);
      float yi0 = fmaxf(oI0[j] + ib.x - LAMC, 0.f);
      float yr1 = fmaxf(oR1[j] + rb.y - LAMC, 0.f);
      float yi1 = fmaxf(oI1[j] + ib.y - LAMC, 0.f);
#pragma unroll
      for (int k2 = 0; k2 < 8; ++k2) {
        float Cv = s_Ct[k2 * 32 + kp], Sv = s_St[k2 * 32 + kp];
        upA[k2] = fmaf(yr0, Cv, upA[k2]); upA[k2] = fmaf(yi0, -Sv, upA[k2]);
        upB[k2] = fmaf(yr1, Cv, upB[k2]); upB[k2] = fmaf(yi1, -Sv, upB[k2]);
      }
    }
#pragma unroll
    for (int k2 = 0; k2 < 8; ++k2) {
      *(float2*)(sp + kg * KD + k2 * MD + d0) = make_float2(upA[k2], upB[k2]);
    }
  }
  __syncthreads();

  // phase 7: reduce u over the 4 kg partials; write u bf16 (kappa=i*8+k2 order)
  if (fused == 0) {
    for (int kk = tid; kk < KD; kk += 384) {
      int i = kk >> 3, k2 = kk & 7;
      int o_ = k2 * MD + i;
      u_out[(long)b * KD + kk] =
          bf16_bits(sp[o_] + sp[KD + o_] + sp[2*KD + o_] + sp[3*KD + o_]);
    }
  } else {
    for (int kk = tid; kk < KD; kk += 384) {
      int i = kk >> 3, k2 = kk & 7;
      int o_ = k2 * MD + i;
      sxr[kk] = sp[o_] + sp[KD + o_] + sp[2*KD + o_] + sp[3*KD + o_];
    }
    __syncthreads();
    int w = tid >> 6, lane = tid & 63;
    for (int o = w; o < MD; o += 6) {
      float p = 0.f;
      for (int kq = lane; kq < KD; kq += 64)
        p = fmaf(sxr[kq], conv_w[o * KD + kq], p);
      p = wred(p);
      if (lane == 0) sxi[1400 + o] = p * (1.0f / 33.0f) + conv_b[o];
    }
  }
  __syncthreads();

  // phase 8: root branch (rhythm conv collapsed) + two LayerNorms
  float* s_g  = sxi;          // 272
  float* s_nm = sxi + 288;    // 172
  for (int c = tid; c < 272; c += 384) {
    float m;
    if (c < TD) m = cosf(t[b] * s_fr[c]);
    else        m = node_mem[(long)node_ids[b] * MD + (c - TD)];
    float hw = 0.5f * (rhythm_w[c * 4 + 1] + rhythm_w[c * 4 + 2]);
    s_g[c] = m * hw;
  }
  __syncthreads();
  if (tid < MD) {
    float acc = 0.f;
    for (int c = 0; c < 272; ++c) acc = fmaf(s_g[c], lin_w[c * MD + tid], acc);
    s_nm[tid] = acc + lin_b[tid];
  }
  __syncthreads();
  float v = (tid < MD) ? s_nm[tid] : 0.f;
  float s1 = wred(v), s2 = wred(v * v);
  if ((tid & 63) == 0) { s_red[tid >> 6] = s1; s_red[8 + (tid >> 6)] = s2; }
  __syncthreads();
  if (tid == 0) {
    float a = 0, q = 0;
    for (int wv = 0; wv < 6; ++wv) { a += s_red[wv]; q += s_red[8 + wv]; }
    float mean = a / 172.0f;
    float var  = q / 172.0f - mean * mean;
    s_red[14] = mean; s_red[15] = rsqrtf(var + 1e-5f);
  }
  __syncthreads();
  float h = 0.f;
  if (tid < MD) h = (v - s_red[14]) * s_red[15] * mb_w[tid] + mb_b[tid];
  __syncthreads();
  float t1 = wred((tid < MD) ? h : 0.f), t2 = wred((tid < MD) ? h * h : 0.f);
  if ((tid & 63) == 0) { s_red[tid >> 6] = t1; s_red[8 + (tid >> 6)] = t2; }
  __syncthreads();
  if (tid == 0) {
    float a = 0, q = 0;
    for (int wv = 0; wv < 6; ++wv) { a += s_red[wv]; q += s_red[8 + wv]; }
    float mean = a / 172.0f;
    float var  = q / 172.0f - mean * mean;
    s_red[14] = mean; s_red[15] = rsqrtf(var + 1e-5f);
  }
  __syncthreads();
  if (tid < MD) {
    float ov = (h - s_red[14]) * s_red[15] * ln_w[tid] + ln_b[tid];
    out[(long)b * MD + tid] = ov + (fused ? sxi[1400 + tid] : 0.f);
  }
}

// ---- Kernel 3: MFMA GEMM out[b,o] += (1/33)*u[b,:].conv_w[o,:] + conv_b[o] ----
// 512 blocks x 256 thr; block = one 16-row M-tile; 4 waves split 11 N-tiles (3/3/3/2)
__global__ __launch_bounds__(256) void k_gemm2(const short* __restrict__ u,
                                               const short* __restrict__ Bfrag,
                                               const float* __restrict__ conv_b,
                                               float* __restrict__ out) {
  const int l = threadIdx.x & 63, w = threadIdx.x >> 6;
  const int m0 = blockIdx.x * 16;
  const int start = w * 3;
  const int cnt = (w < 3) ? 3 : 2;
  f32x4 acc[3];
  acc[0] = (f32x4)(0.f); acc[1] = (f32x4)(0.f); acc[2] = (f32x4)(0.f);
  const int arow = m0 + (l & 15);
  const short* ap = u + (long)arow * KD + (l >> 4) * 8;
  for (int s = 0; s < 43; ++s) {
    short8 a = *(const short8*)(ap + s * 32);
#pragma unroll
    for (int t = 0; t < 3; ++t) {
      if (t < cnt) {
        long n0 = start + t;
        short8 bb = *(const short8*)(Bfrag + ((n0 * 43 + s) * 64 + l) * 8);
        acc[t] = __builtin_amdgcn_mfma_f32_16x16x32_bf16(a, bb, acc[t], 0, 0, 0);
      }
    }
  }
#pragma unroll
  for (int t = 0; t < 3; ++t) {
    if (t < cnt) {
      int n = (start + t) * 16 + (l & 15);
      if (n < MD) {
        float cb = conv_b[n];
#pragma unroll
        for (int r = 0; r < 4; ++r) {
          int m = m0 + (l >> 4) * 4 + r;
          out[(long)m * MD + n] += acc[t][r] * (1.0f / 33.0f) + cb;
        }
      }
    }
  }
}

extern "C" void kernel_launch(void* const* d_in, const int* in_sizes, int n_in,
                              void* d_out, int out_size, void* d_ws, size_t ws_size,
                              hipStream_t stream) {
  const int* node_ids = (const int*)d_in[0];
  const int* nbr_id   = (const int*)d_in[1];
  const float* t  = (const float*)d_in[2];
  const float* nt = (const float*)d_in[3];
  const float* node_mem = (const float*)d_in[4];
  const float* r1 = (const float*)d_in[5];
  const float* i1 = (const float*)d_in[6];
  const float* rb1 = (const float*)d_in[7];
  const float* ib1 = (const float*)d_in[8];
  const float* conv_w = (const float*)d_in[9];
  const float* conv_b = (const float*)d_in[10];
  const float* rhythm_w = (const float*)d_in[11];
  const float* lin_w = (const float*)d_in[12];
  const float* lin_b = (const float*)d_in[13];
  const float* mb_w = (const float*)d_in[14];
  const float* mb_b = (const float*)d_in[15];
  const float* ln_w = (const float*)d_in[16];
  const float* ln_b = (const float*)d_in[17];
  float* out = (float*)d_out;
  float* wsf = (float*)d_ws;

  const size_t u_bytes = (size_t)B_ * KD * 2;            // bf16 u
  const size_t bf_bytes = (size_t)11 * 43 * 64 * 8 * 2;  // bf16 conv B-frags
  const size_t need = 256 + u_bytes + bf_bytes;
  int fused = (ws_size >= need) ? 0 : 1;
  short* u = (short*)((char*)d_ws + 256);
  short* Bfrag = (short*)((char*)d_ws + 256 + u_bytes);

  hipMemsetAsync(d_ws, 0, 16, stream);
  k_mean<<<1024, 256, 0, stream>>>(nbr_id, t, nt, wsf);
  if (!fused)
    k_prep<<<(11 * 43 * 64 * 8 + 255) / 256, 256, 0, stream>>>(conv_w, Bfrag);
  k_main<<<B_, 384, 0, stream>>>(node_ids, nbr_id, t, nt, node_mem, r1, i1,
                                 rb1, ib1, conv_w, conv_b, rhythm_w, lin_w,
                                 lin_b, mb_w, mb_b, ln_w, ln_b, wsf, u, out, fused);
  if (!fused)
    k_gemm2<<<512, 256, 0, stream>>>(u, Bfrag, conv_b, out);
}

// Round 3
// 881.259 us; speedup vs baseline: 1.7828x; 1.4457x over previous
//
#include <hip/hip_runtime.h>
#include <hip/hip_bf16.h>
#include <math.h>

#define B_ 8192
#define NN 32
#define TD 100
#define MD 172
#define KD 1376   // MD*8
#define TAUC 0.3f
#define LAMC 0.01f

typedef __attribute__((ext_vector_type(8))) short short8;
typedef __attribute__((ext_vector_type(4))) float f32x4;

// ws layout (ws_size >= 45MB evidenced in R1/R2; need ~23.2MB)
#define WS_U_OFF    256
#define U_BYTES     ((size_t)B_ * KD * 2)
#define CONVB_ELEMS (11 * 43 * 64 * 8)
#define WBIG_ELEMS  (22 * 7 * 64 * 8)      // 78848
#define CS_ELEMS    (2 * 64 * 8)           // 1024

__device__ __forceinline__ float wred(float v) {
#pragma unroll
  for (int o = 32; o > 0; o >>= 1) v += __shfl_down(v, o, 64);
  return v;
}

__device__ __forceinline__ short bf16_bits(float f) {
  __hip_bfloat16 h = __float2bfloat16(f);
  return *(short*)&h;
}

__device__ __forceinline__ unsigned pack2(float a, float b) {
  return (unsigned)(unsigned short)bf16_bits(a) |
         ((unsigned)(unsigned short)bf16_bits(b) << 16);
}

// ---- Kernel 1: global energy mean via Parseval ----
__global__ __launch_bounds__(256) void k_mean(const int* __restrict__ nid,
                                              const float* __restrict__ t,
                                              const float* __restrict__ nt,
                                              float* __restrict__ ws) {
  __shared__ float fr[TD];
  __shared__ float part[4];
  int tid = threadIdx.x;
  if (tid < TD) fr[tid] = (float)exp(-9.0 * (double)tid / 99.0 * 2.302585092994045684);
  __syncthreads();
  int idx = blockIdx.x * 256 + tid;
  int b = idx >> 5;
  float s = 0.f;
  if (nid[idx] != 0) {
    float dt = t[b] - nt[idx];
    for (int c = 0; c < TD; ++c) { float v = cosf(dt * fr[c]); s = fmaf(v, v, s); }
  }
  s = wred(s);
  if ((tid & 63) == 0) part[tid >> 6] = s;
  __syncthreads();
  if (tid == 0) atomicAdd(ws, part[0] + part[1] + part[2] + part[3]);
}

// ---- Kernel 1b: conv_w^T -> bf16 B-fragments (16x16x32), unchanged from R2 ----
__global__ __launch_bounds__(256) void k_prep(const float* __restrict__ conv_w,
                                              short* __restrict__ Bfrag) {
  int idx = blockIdx.x * 256 + threadIdx.x;
  if (idx >= CONVB_ELEMS) return;
  int j = idx & 7;
  int l = (idx >> 3) & 63;
  int s = (idx >> 9) % 43;
  int n0 = idx / (43 * 64 * 8);
  int k = s * 32 + (l >> 4) * 8 + j;
  int col = n0 * 16 + (l & 15);
  float v = (col < MD) ? conv_w[(long)col * KD + k] : 0.f;
  Bfrag[idx] = bf16_bits(v);
}

// ---- Kernel 1c: Wbig B-fragments (224x352: [[r1,-i1],[i1,r1]]) + CS A-fragments ----
__global__ __launch_bounds__(256) void k_prep3(const float* __restrict__ r1,
                                               const float* __restrict__ i1,
                                               short* __restrict__ Wfrag,
                                               short* __restrict__ CSfrag) {
  int idx = blockIdx.x * 256 + threadIdx.x;
  const float inv_s = 0.17677669529663687f;
  if (idx < WBIG_ELEMS) {
    int j = idx & 7;
    int l = (idx >> 3) & 63;
    int s = (idx % 3584) >> 9;     // 3584 = 7*64*8
    int n0 = idx / 3584;
    int k = s * 32 + (l >> 4) * 8 + j;
    int col = n0 * 16 + (l & 15);
    float v = 0.f;
    if (k < 200) {
      if (n0 < 11) {               // O_r columns: d = col
        int d = col;
        if (d < MD) v = (k < 100) ? r1[k * MD + d] : -i1[(k - 100) * MD + d];
      } else {                     // O_i columns: d = col - 176
        int d = col - 176;
        if (d >= 0 && d < MD) v = (k < 100) ? i1[k * MD + d] : r1[(k - 100) * MD + d];
      }
    }
    Wfrag[idx] = bf16_bits(v);
  } else if (idx < WBIG_ELEMS + CS_ELEMS) {
    int idx2 = idx - WBIG_ELEMS;
    int j = idx2 & 7;
    int l = (idx2 >> 3) & 63;
    int s = idx2 >> 9;             // 0..1
    int row = l & 15;              // k2
    int kq = s * 32 + (l >> 4) * 8 + j;   // 0..63
    float v = 0.f;
    if (row < 8) {
      int kp = (kq < 32) ? kq : kq - 32;
      int lo = row - 4; if (lo < 0) lo = 0;
      int hi = row + 28; if (hi > 31) hi = 31;
      double cs = 0.0, ss = 0.0;
      for (int n = lo; n <= hi; ++n) {
        double ang = 0.19634954084936207740 * (double)((kp * n) & 31);
        cs += cos(ang); ss += sin(ang);
      }
      v = ((kq < 32) ? (float)cs : -(float)ss) * inv_s;
    }
    CSfrag[idx2] = bf16_bits(v);
  }
}

// ---- Kernel 2: per-b fused pipeline (MFMA phase 6) ----
__global__ __launch_bounds__(384) void k_main(
    const int* __restrict__ node_ids, const int* __restrict__ nbr_id,
    const float* __restrict__ t, const float* __restrict__ nt,
    const float* __restrict__ node_mem,
    const float* __restrict__ rb1, const float* __restrict__ ib1,
    const float* __restrict__ rhythm_w, const float* __restrict__ lin_w,
    const float* __restrict__ lin_b, const float* __restrict__ mb_w,
    const float* __restrict__ mb_b, const float* __restrict__ ln_w,
    const float* __restrict__ ln_b, const float* __restrict__ ws0,
    const short* __restrict__ Wfrag, const short* __restrict__ CSfrag,
    short* __restrict__ u_out, float* __restrict__ out) {
  // union buffer: [0,14848): tfeat f32 (12800) -> sA bf16 32x232
  //               [14848,40192): sxr16/sxi16 bf16 32x112 each -> Y bf16 176x72
  __shared__ __align__(16) unsigned char s_buf[40192];
  __shared__ float s_fr[TD];
  __shared__ float s_c32[32], s_s32[32], s_dt[32], s_z[32];
  __shared__ float s_energy[32], s_msk[32];
  __shared__ float s_red[16];
  __shared__ float s_g[272], s_nm[MD];

  float* tf = (float*)s_buf;
  short* sA = (short*)s_buf;                    // 32 x 232
  short* sxr16 = (short*)(s_buf + 14848);       // 32 x 112
  short* sxi16 = sxr16 + 3584;
  short* Y = (short*)(s_buf + 14848);           // 176 x 72

  const int tid = threadIdx.x;
  const int b = blockIdx.x;
  const float inv_s = 0.17677669529663687f;

  // P1: twiddles, dt, freqs, energy init
  if (tid < 32) {
    double ang = 0.19634954084936207740 * (double)tid;
    s_c32[tid] = (float)cos(ang);
    s_s32[tid] = (float)sin(ang);
    int gi = b * NN + tid;
    int id = nbr_id[gi];
    float d = t[b] - nt[gi];
    s_z[tid]  = (id == 0) ? 0.f : 1.f;
    s_dt[tid] = (id == 0) ? 0.f : d;
    s_energy[tid] = 0.f;
  }
  if (tid < TD) s_fr[tid] = (float)exp(-9.0 * (double)tid / 99.0 * 2.302585092994045684);
  __syncthreads();

  // P2: tfeat f32 into tf
  for (int idx = tid; idx < NN * TD; idx += 384) {
    int n = idx / TD, c = idx - n * TD;
    tf[idx] = s_z[n] * cosf(s_dt[n] * s_fr[c]);
  }
  __syncthreads();

  // P3: DFT over n (k=0..16 + mirror), bf16 store + fp32 energy
  for (int task = tid; task < 17 * 25; task += 384) {
    int k = task / 25, c4 = (task - k * 25) * 4;
    float ar0=0,ar1=0,ar2=0,ar3=0, ai0=0,ai1=0,ai2=0,ai3=0;
    for (int n = 0; n < NN; ++n) {
      float4 a = *(const float4*)(tf + n * TD + c4);
      int j = (k * n) & 31;
      float cw = s_c32[j], sw = s_s32[j];
      ar0 = fmaf(a.x, cw, ar0); ai0 = fmaf(a.x, -sw, ai0);
      ar1 = fmaf(a.y, cw, ar1); ai1 = fmaf(a.y, -sw, ai1);
      ar2 = fmaf(a.z, cw, ar2); ai2 = fmaf(a.z, -sw, ai2);
      ar3 = fmaf(a.w, cw, ar3); ai3 = fmaf(a.w, -sw, ai3);
    }
    ar0*=inv_s; ar1*=inv_s; ar2*=inv_s; ar3*=inv_s;
    ai0*=inv_s; ai1*=inv_s; ai2*=inv_s; ai3*=inv_s;
    float e = ar0*ar0+ar1*ar1+ar2*ar2+ar3*ar3 + ai0*ai0+ai1*ai1+ai2*ai2+ai3*ai3;
    atomicAdd(&s_energy[k], e);
    uint2 vr = make_uint2(pack2(ar0, ar1), pack2(ar2, ar3));
    uint2 vi = make_uint2(pack2(ai0, ai1), pack2(ai2, ai3));
    *(uint2*)(sxr16 + k * 112 + c4) = vr;
    *(uint2*)(sxi16 + k * 112 + c4) = vi;
    if (k >= 1 && k <= 15) {
      uint2 vin = make_uint2(pack2(-ai0, -ai1), pack2(-ai2, -ai3));
      *(uint2*)(sxr16 + (32 - k) * 112 + c4) = vr;
      *(uint2*)(sxi16 + (32 - k) * 112 + c4) = vin;
    }
  }
  __syncthreads();

  // P4: mask per k
  if (tid < 32) {
    int ks = (tid <= 16) ? tid : 32 - tid;
    float mean = ws0[0] * (1.0f / 262144.0f);
    s_msk[tid] = (s_energy[ks] >= TAUC * (mean + 1e-6f)) ? 1.f : 0.f;
  }
  __syncthreads();

  // P5: repack masked [Xr|Xi|0pad] -> sA bf16 32x232 (A-fragment-friendly row-major)
  for (int t4 = tid; t4 < 32 * 58; t4 += 384) {
    int row = t4 / 58, c4 = (t4 - row * 58) * 4;
    uint2 v = make_uint2(0u, 0u);
    if (c4 < 100)      v = *(const uint2*)(sxr16 + row * 112 + c4);
    else if (c4 < 200) v = *(const uint2*)(sxi16 + row * 112 + (c4 - 100));
    if (s_msk[row] == 0.f) v = make_uint2(0u, 0u);
    *(uint2*)(sA + row * 232 + c4) = v;
  }
  __syncthreads();

  // P6: MFMA O = [Xr|Xi] @ Wbig  (M=32 -> waves 0-2: m-tile 0, waves 3-5: m-tile 1)
  {
    const int l = tid & 63, w = tid >> 6;
    const int mside = (w >= 3) ? 1 : 0;
    const int wn = w % 3;
    short8 afrag[7];
    const short* ab = sA + (mside * 16 + (l & 15)) * 232 + ((l >> 4) << 3);
#pragma unroll
    for (int s = 0; s < 7; ++s) afrag[s] = *(const short8*)(ab + s * 32);
    for (int n = wn; n < 22; n += 3) {
      f32x4 acc = (f32x4)(0.f);
#pragma unroll
      for (int s = 0; s < 7; ++s) {
        short8 bb = *(const short8*)(Wfrag + (((n * 7 + s) << 6) + l) * 8);
        acc = __builtin_amdgcn_mfma_f32_16x16x32_bf16(afrag[s], bb, acc, 0, 0, 0);
      }
      int side = (n >= 11) ? 1 : 0;
      int d = n * 16 + (l & 15) - side * 176;
      bool valid = (d >= 0 && d < MD);
      float bias = valid ? (side ? ib1[d] : rb1[d]) : 0.f;
      float y0 = valid ? fmaxf(acc[0] + bias - LAMC, 0.f) : 0.f;
      float y1 = valid ? fmaxf(acc[1] + bias - LAMC, 0.f) : 0.f;
      float y2 = valid ? fmaxf(acc[2] + bias - LAMC, 0.f) : 0.f;
      float y3 = valid ? fmaxf(acc[3] + bias - LAMC, 0.f) : 0.f;
      // Y[d][k'] transposed store: k' = side*32 + mside*16 + quad*4 + r
      int kp0 = side * 32 + mside * 16 + ((l >> 4) << 2);
      int dd = n * 16 + (l & 15) - side * 176;
      if (dd >= 0 && dd < 176) {
        uint2 pv = make_uint2(pack2(y0, y1), pack2(y2, y3));
        *(uint2*)(Y + dd * 72 + kp0) = pv;
      }
    }
  }
  __syncthreads();

  // P7: u-MFMA  u[16(8 used) x 176] = CS[16x64] @ Y^T ; store u_out bf16
  {
    const int l = tid & 63, w = tid >> 6;
    short8 cs0 = *(const short8*)(CSfrag + (l << 3));
    short8 cs1 = *(const short8*)(CSfrag + ((64 + l) << 3));
    for (int nu = w; nu < 11; nu += 6) {
      const short* yb = Y + (nu * 16 + (l & 15)) * 72 + ((l >> 4) << 3);
      short8 b0 = *(const short8*)(yb);
      short8 b1 = *(const short8*)(yb + 32);
      f32x4 acc = (f32x4)(0.f);
      acc = __builtin_amdgcn_mfma_f32_16x16x32_bf16(cs0, b0, acc, 0, 0, 0);
      acc = __builtin_amdgcn_mfma_f32_16x16x32_bf16(cs1, b1, acc, 0, 0, 0);
      int q = l >> 4;
      int d = nu * 16 + (l & 15);
      if (q < 2 && d < MD) {
        uint2 pv = make_uint2(pack2(acc[0], acc[1]), pack2(acc[2], acc[3]));
        *(uint2*)(u_out + (long)b * KD + d * 8 + q * 4) = pv;
      }
    }
  }

  // P8: root branch + two LayerNorms (independent of P6/P7 LDS)
  for (int c = tid; c < 272; c += 384) {
    float m;
    if (c < TD) m = cosf(t[b] * s_fr[c]);
    else        m = node_mem[(long)node_ids[b] * MD + (c - TD)];
    float hw = 0.5f * (rhythm_w[c * 4 + 1] + rhythm_w[c * 4 + 2]);
    s_g[c] = m * hw;
  }
  __syncthreads();
  if (tid < MD) {
    float acc = 0.f;
    for (int c = 0; c < 272; ++c) acc = fmaf(s_g[c], lin_w[c * MD + tid], acc);
    s_nm[tid] = acc + lin_b[tid];
  }
  __syncthreads();
  float v = (tid < MD) ? s_nm[tid] : 0.f;
  float s1 = wred(v), s2 = wred(v * v);
  if ((tid & 63) == 0) { s_red[tid >> 6] = s1; s_red[8 + (tid >> 6)] = s2; }
  __syncthreads();
  if (tid == 0) {
    float a = 0, q = 0;
    for (int wv = 0; wv < 6; ++wv) { a += s_red[wv]; q += s_red[8 + wv]; }
    float mean = a / 172.0f;
    float var  = q / 172.0f - mean * mean;
    s_red[14] = mean; s_red[15] = rsqrtf(var + 1e-5f);
  }
  __syncthreads();
  float h = 0.f;
  if (tid < MD) h = (v - s_red[14]) * s_red[15] * mb_w[tid] + mb_b[tid];
  __syncthreads();
  float t1 = wred((tid < MD) ? h : 0.f), t2 = wred((tid < MD) ? h * h : 0.f);
  if ((tid & 63) == 0) { s_red[tid >> 6] = t1; s_red[8 + (tid >> 6)] = t2; }
  __syncthreads();
  if (tid == 0) {
    float a = 0, q = 0;
    for (int wv = 0; wv < 6; ++wv) { a += s_red[wv]; q += s_red[8 + wv]; }
    float mean = a / 172.0f;
    float var  = q / 172.0f - mean * mean;
    s_red[14] = mean; s_red[15] = rsqrtf(var + 1e-5f);
  }
  __syncthreads();
  if (tid < MD) {
    float ov = (h - s_red[14]) * s_red[15] * ln_w[tid] + ln_b[tid];
    out[(long)b * MD + tid] = ov;
  }
}

// ---- Kernel 3: MFMA GEMM out[b,o] += (1/33)*u.conv_w + conv_b (unchanged) ----
__global__ __launch_bounds__(256) void k_gemm2(const short* __restrict__ u,
                                               const short* __restrict__ Bfrag,
                                               const float* __restrict__ conv_b,
                                               float* __restrict__ out) {
  const int l = threadIdx.x & 63, w = threadIdx.x >> 6;
  const int m0 = blockIdx.x * 16;
  const int start = w * 3;
  const int cnt = (w < 3) ? 3 : 2;
  f32x4 acc[3];
  acc[0] = (f32x4)(0.f); acc[1] = (f32x4)(0.f); acc[2] = (f32x4)(0.f);
  const int arow = m0 + (l & 15);
  const short* ap = u + (long)arow * KD + (l >> 4) * 8;
  for (int s = 0; s < 43; ++s) {
    short8 a = *(const short8*)(ap + s * 32);
#pragma unroll
    for (int t = 0; t < 3; ++t) {
      if (t < cnt) {
        long n0 = start + t;
        short8 bb = *(const short8*)(Bfrag + ((n0 * 43 + s) * 64 + l) * 8);
        acc[t] = __builtin_amdgcn_mfma_f32_16x16x32_bf16(a, bb, acc[t], 0, 0, 0);
      }
    }
  }
#pragma unroll
  for (int t = 0; t < 3; ++t) {
    if (t < cnt) {
      int n = (start + t) * 16 + (l & 15);
      if (n < MD) {
        float cb = conv_b[n];
#pragma unroll
        for (int r = 0; r < 4; ++r) {
          int m = m0 + (l >> 4) * 4 + r;
          out[(long)m * MD + n] += acc[t][r] * (1.0f / 33.0f) + cb;
        }
      }
    }
  }
}

extern "C" void kernel_launch(void* const* d_in, const int* in_sizes, int n_in,
                              void* d_out, int out_size, void* d_ws, size_t ws_size,
                              hipStream_t stream) {
  const int* node_ids = (const int*)d_in[0];
  const int* nbr_id   = (const int*)d_in[1];
  const float* t  = (const float*)d_in[2];
  const float* nt = (const float*)d_in[3];
  const float* node_mem = (const float*)d_in[4];
  const float* r1 = (const float*)d_in[5];
  const float* i1 = (const float*)d_in[6];
  const float* rb1 = (const float*)d_in[7];
  const float* ib1 = (const float*)d_in[8];
  const float* conv_w = (const float*)d_in[9];
  const float* conv_b = (const float*)d_in[10];
  const float* rhythm_w = (const float*)d_in[11];
  const float* lin_w = (const float*)d_in[12];
  const float* lin_b = (const float*)d_in[13];
  const float* mb_w = (const float*)d_in[14];
  const float* mb_b = (const float*)d_in[15];
  const float* ln_w = (const float*)d_in[16];
  const float* ln_b = (const float*)d_in[17];
  float* out = (float*)d_out;
  float* wsf = (float*)d_ws;

  char* base = (char*)d_ws;
  short* u     = (short*)(base + WS_U_OFF);
  short* convB = (short*)(base + WS_U_OFF + U_BYTES);
  short* Wfrag = (short*)(base + WS_U_OFF + U_BYTES + (size_t)CONVB_ELEMS * 2);
  short* CSfrag = Wfrag + WBIG_ELEMS;
  // need ~23.2MB; ws_size >= 45MB evidenced (R1 ran the fp32-u path)

  hipMemsetAsync(d_ws, 0, 16, stream);
  k_mean<<<1024, 256, 0, stream>>>(nbr_id, t, nt, wsf);
  k_prep<<<(CONVB_ELEMS + 255) / 256, 256, 0, stream>>>(conv_w, convB);
  k_prep3<<<(WBIG_ELEMS + CS_ELEMS) / 256, 256, 0, stream>>>(r1, i1, Wfrag, CSfrag);
  k_main<<<B_, 384, 0, stream>>>(node_ids, nbr_id, t, nt, node_mem,
                                 rb1, ib1, rhythm_w, lin_w, lin_b,
                                 mb_w, mb_b, ln_w, ln_b, wsf,
                                 Wfrag, CSfrag, u, out);
  k_gemm2<<<512, 256, 0, stream>>>(u, convB, conv_b, out);
}

// Round 4
// 652.223 us; speedup vs baseline: 2.4088x; 1.3512x over previous
//
#include <hip/hip_runtime.h>
#include <hip/hip_bf16.h>
#include <math.h>

#define B_ 8192
#define NN 32
#define TD 100
#define MD 172
#define KD 1376   // MD*8
#define TAUC 0.3f
#define LAMC 0.01f

typedef __attribute__((ext_vector_type(8))) short short8;
typedef __attribute__((ext_vector_type(4))) float f32x4;

// ws layout (ws_size >= 45MB evidenced; need ~23.3MB)
#define WS_U_OFF    256
#define U_BYTES     ((size_t)B_ * KD * 2)
#define CONVB_ELEMS (11 * 43 * 64 * 8)     // 242688
#define WBIG_ELEMS  (22 * 7 * 64 * 8)      // 78848
#define CS_ELEMS    (2 * 64 * 8)           // 1024
#define ROOT_ELEMS  (11 * 9 * 64 * 8)      // 50688

__device__ __forceinline__ float wred(float v) {
#pragma unroll
  for (int o = 32; o > 0; o >>= 1) v += __shfl_down(v, o, 64);
  return v;
}

__device__ __forceinline__ short bf16_bits(float f) {
  __hip_bfloat16 h = __float2bfloat16(f);
  return *(short*)&h;
}

__device__ __forceinline__ unsigned pack2(float a, float b) {
  return (unsigned)(unsigned short)bf16_bits(a) |
         ((unsigned)(unsigned short)bf16_bits(b) << 16);
}

// ---- Kernel 1: global energy mean via Parseval ----
__global__ __launch_bounds__(256) void k_mean(const int* __restrict__ nid,
                                              const float* __restrict__ t,
                                              const float* __restrict__ nt,
                                              float* __restrict__ ws) {
  __shared__ float fr[TD];
  __shared__ float part[4];
  int tid = threadIdx.x;
  if (tid < TD) fr[tid] = (float)exp(-9.0 * (double)tid / 99.0 * 2.302585092994045684);
  __syncthreads();
  int idx = blockIdx.x * 256 + tid;
  int b = idx >> 5;
  float s = 0.f;
  if (nid[idx] != 0) {
    float dt = t[b] - nt[idx];
    for (int c = 0; c < TD; ++c) { float v = cosf(dt * fr[c]); s = fmaf(v, v, s); }
  }
  s = wred(s);
  if ((tid & 63) == 0) part[tid >> 6] = s;
  __syncthreads();
  if (tid == 0) atomicAdd(ws, part[0] + part[1] + part[2] + part[3]);
}

// ---- Kernel 1b: conv_w^T -> bf16 B-fragments (validated R2/R3) ----
__global__ __launch_bounds__(256) void k_prep(const float* __restrict__ conv_w,
                                              short* __restrict__ Bfrag) {
  int idx = blockIdx.x * 256 + threadIdx.x;
  if (idx >= CONVB_ELEMS) return;
  int j = idx & 7;
  int l = (idx >> 3) & 63;
  int s = (idx >> 9) % 43;
  int n0 = idx / (43 * 64 * 8);
  int k = s * 32 + (l >> 4) * 8 + j;
  int col = n0 * 16 + (l & 15);
  float v = (col < MD) ? conv_w[(long)col * KD + k] : 0.f;
  Bfrag[idx] = bf16_bits(v);
}

// ---- Kernel 1c: Wbig + CS (validated R3) + root lin_w' B-fragments ----
__global__ __launch_bounds__(256) void k_prep3(const float* __restrict__ r1,
                                               const float* __restrict__ i1,
                                               const float* __restrict__ rhythm_w,
                                               const float* __restrict__ lin_w,
                                               short* __restrict__ Wfrag,
                                               short* __restrict__ CSfrag,
                                               short* __restrict__ Rfrag) {
  int idx = blockIdx.x * 256 + threadIdx.x;
  const float inv_s = 0.17677669529663687f;
  if (idx < WBIG_ELEMS) {
    int j = idx & 7;
    int l = (idx >> 3) & 63;
    int s = (idx % 3584) >> 9;     // 3584 = 7*64*8
    int n0 = idx / 3584;
    int k = s * 32 + (l >> 4) * 8 + j;
    int col = n0 * 16 + (l & 15);
    float v = 0.f;
    if (k < 200) {
      if (n0 < 11) {
        int d = col;
        if (d < MD) v = (k < 100) ? r1[k * MD + d] : -i1[(k - 100) * MD + d];
      } else {
        int d = col - 176;
        if (d >= 0 && d < MD) v = (k < 100) ? i1[k * MD + d] : r1[(k - 100) * MD + d];
      }
    }
    Wfrag[idx] = bf16_bits(v);
  } else if (idx < WBIG_ELEMS + CS_ELEMS) {
    int idx2 = idx - WBIG_ELEMS;
    int j = idx2 & 7;
    int l = (idx2 >> 3) & 63;
    int s = idx2 >> 9;
    int row = l & 15;              // k2
    int kq = s * 32 + (l >> 4) * 8 + j;
    float v = 0.f;
    if (row < 8) {
      int kp = (kq < 32) ? kq : kq - 32;
      int lo = row - 4; if (lo < 0) lo = 0;
      int hi = row + 28; if (hi > 31) hi = 31;
      double cs = 0.0, ss = 0.0;
      for (int n = lo; n <= hi; ++n) {
        double ang = 0.19634954084936207740 * (double)((kp * n) & 31);
        cs += cos(ang); ss += sin(ang);
      }
      v = ((kq < 32) ? (float)cs : -(float)ss) * inv_s;
    }
    CSfrag[idx2] = bf16_bits(v);
  } else if (idx < WBIG_ELEMS + CS_ELEMS + ROOT_ELEMS) {
    int idx4 = idx - WBIG_ELEMS - CS_ELEMS;
    int n = idx4 / 4608;           // 4608 = 9*64*8
    int rem = idx4 % 4608;
    int s = rem >> 9;
    int l = (rem >> 3) & 63;
    int j = rem & 7;
    int k = s * 32 + (l >> 4) * 8 + j;     // 0..287
    int col = n * 16 + (l & 15);           // 0..175
    float v = 0.f;
    if (k < 272 && col < MD) {
      float hw = 0.5f * (rhythm_w[k * 4 + 1] + rhythm_w[k * 4 + 2]);
      v = hw * lin_w[k * MD + col];
    }
    Rfrag[idx4] = bf16_bits(v);
  }
}

// ---- Kernel 2: per-b neighbor pipeline (DFT -> mask -> MFMA -> u) ----
__global__ __launch_bounds__(384, 8) void k_main(
    const int* __restrict__ nbr_id, const float* __restrict__ t,
    const float* __restrict__ nt, const float* __restrict__ rb1,
    const float* __restrict__ ib1, const float* __restrict__ ws0,
    const short* __restrict__ Wfrag, const short* __restrict__ CSfrag,
    short* __restrict__ u_out) {
  __shared__ __align__(16) short sA[32 * 232];           // 14848 B: masked [Xr|Xi|pad] bf16
  __shared__ __align__(16) unsigned char s_un[12800];    // tf f32 [32][100] -> Y bf16 [176][32]
  __shared__ float s_fr[TD];
  __shared__ float s_c32[32], s_s32[32], s_dt[32], s_z[32];
  __shared__ float s_energy[32];

  float* tf = (float*)s_un;
  short* Y = (short*)s_un;
  const int tid = threadIdx.x;
  const int b = blockIdx.x;
  const int l = tid & 63, w = tid >> 6;
  const float inv_s = 0.17677669529663687f;

  // P1
  if (tid < 32) {
    double ang = 0.19634954084936207740 * (double)tid;
    s_c32[tid] = (float)cos(ang);
    s_s32[tid] = (float)sin(ang);
    int gi = b * NN + tid;
    int id = nbr_id[gi];
    float d = t[b] - nt[gi];
    s_z[tid]  = (id == 0) ? 0.f : 1.f;
    s_dt[tid] = (id == 0) ? 0.f : d;
    s_energy[tid] = 0.f;
  }
  if (tid < TD) s_fr[tid] = (float)exp(-9.0 * (double)tid / 99.0 * 2.302585092994045684);
  __syncthreads();

  // P2: tfeat f32 + zero sA pad cols 200..231
  for (int idx = tid; idx < NN * TD; idx += 384) {
    int n = idx / TD, c = idx - n * TD;
    tf[idx] = s_z[n] * cosf(s_dt[n] * s_fr[c]);
  }
  if (tid < 256) {
    int row = tid >> 3, q = tid & 7;
    *(uint2*)(sA + row * 232 + 200 + q * 4) = make_uint2(0u, 0u);
  }
  __syncthreads();

  // P3: fp32 DFT over n (k<=16 + mirror), bf16 into sA, fp32 energy
  for (int task = tid; task < 17 * 25; task += 384) {
    int k = task / 25, c4 = (task - k * 25) * 4;
    float ar0=0,ar1=0,ar2=0,ar3=0, ai0=0,ai1=0,ai2=0,ai3=0;
    for (int n = 0; n < NN; ++n) {
      float4 a = *(const float4*)(tf + n * TD + c4);
      int j = (k * n) & 31;
      float cw = s_c32[j], sw = s_s32[j];
      ar0 = fmaf(a.x, cw, ar0); ai0 = fmaf(a.x, -sw, ai0);
      ar1 = fmaf(a.y, cw, ar1); ai1 = fmaf(a.y, -sw, ai1);
      ar2 = fmaf(a.z, cw, ar2); ai2 = fmaf(a.z, -sw, ai2);
      ar3 = fmaf(a.w, cw, ar3); ai3 = fmaf(a.w, -sw, ai3);
    }
    ar0*=inv_s; ar1*=inv_s; ar2*=inv_s; ar3*=inv_s;
    ai0*=inv_s; ai1*=inv_s; ai2*=inv_s; ai3*=inv_s;
    float e = ar0*ar0+ar1*ar1+ar2*ar2+ar3*ar3 + ai0*ai0+ai1*ai1+ai2*ai2+ai3*ai3;
    atomicAdd(&s_energy[k], e);
    uint2 vr = make_uint2(pack2(ar0, ar1), pack2(ar2, ar3));
    uint2 vi = make_uint2(pack2(ai0, ai1), pack2(ai2, ai3));
    *(uint2*)(sA + k * 232 + c4) = vr;
    *(uint2*)(sA + k * 232 + 100 + c4) = vi;
    if (k >= 1 && k <= 15) {
      uint2 vin = make_uint2(pack2(-ai0, -ai1), pack2(-ai2, -ai3));
      *(uint2*)(sA + (32 - k) * 232 + c4) = vr;
      *(uint2*)(sA + (32 - k) * 232 + 100 + c4) = vin;
    }
  }
  __syncthreads();

  // P5: zero rows failing the energy threshold (mask fused, no extra barrier)
  {
    float gth = TAUC * (ws0[0] * (1.0f / 262144.0f) + 1e-6f);
    for (int idx = tid; idx < 800; idx += 384) {
      int row = idx / 25, q = idx - row * 25;
      int ks = (row <= 16) ? row : 32 - row;
      if (s_energy[ks] < gth)
        *(uint4*)((char*)sA + row * 464 + q * 16) = make_uint4(0u,0u,0u,0u);
    }
  }
  __syncthreads();

  // P6a: side 0 (O_r), 2 m-tiles x 11 n-tiles over 6 waves
  const int mside = (w >= 3) ? 1 : 0;
  const int wn = w % 3;
  short8 afrag[7];
  {
    const short* ab = sA + (mside * 16 + (l & 15)) * 232 + ((l >> 4) << 3);
#pragma unroll
    for (int s = 0; s < 7; ++s) afrag[s] = *(const short8*)(ab + s * 32);
  }
  for (int n = wn; n < 11; n += 3) {
    f32x4 acc = (f32x4)(0.f);
#pragma unroll
    for (int s = 0; s < 7; ++s) {
      short8 bb = *(const short8*)(Wfrag + (((n * 7 + s) * 64) + l) * 8);
      acc = __builtin_amdgcn_mfma_f32_16x16x32_bf16(afrag[s], bb, acc, 0, 0, 0);
    }
    int d = n * 16 + (l & 15);
    bool valid = (d < MD);
    float bias = valid ? rb1[d] : 0.f;
    float y0 = valid ? fmaxf(acc[0] + bias - LAMC, 0.f) : 0.f;
    float y1 = valid ? fmaxf(acc[1] + bias - LAMC, 0.f) : 0.f;
    float y2 = valid ? fmaxf(acc[2] + bias - LAMC, 0.f) : 0.f;
    float y3 = valid ? fmaxf(acc[3] + bias - LAMC, 0.f) : 0.f;
    *(uint2*)(Y + d * 32 + mside * 16 + ((l >> 4) << 2)) =
        make_uint2(pack2(y0, y1), pack2(y2, y3));
  }
  __syncthreads();

  // P7a: u partial = CS_r @ Y_r
  f32x4 uacc[2];
  uacc[0] = (f32x4)(0.f); uacc[1] = (f32x4)(0.f);
  {
    short8 cs0 = *(const short8*)(CSfrag + (l << 3));
#pragma unroll
    for (int ti = 0; ti < 2; ++ti) {
      int nu = w + 6 * ti;
      if (nu < 11) {
        short8 bfr = *(const short8*)(Y + (nu * 16 + (l & 15)) * 32 + ((l >> 4) << 3));
        uacc[ti] = __builtin_amdgcn_mfma_f32_16x16x32_bf16(cs0, bfr, uacc[ti], 0, 0, 0);
      }
    }
  }
  __syncthreads();

  // P6b: side 1 (O_i) overwrites Y
  for (int n = wn; n < 11; n += 3) {
    f32x4 acc = (f32x4)(0.f);
    int nw = n + 11;
#pragma unroll
    for (int s = 0; s < 7; ++s) {
      short8 bb = *(const short8*)(Wfrag + (((nw * 7 + s) * 64) + l) * 8);
      acc = __builtin_amdgcn_mfma_f32_16x16x32_bf16(afrag[s], bb, acc, 0, 0, 0);
    }
    int d = n * 16 + (l & 15);
    bool valid = (d < MD);
    float bias = valid ? ib1[d] : 0.f;
    float y0 = valid ? fmaxf(acc[0] + bias - LAMC, 0.f) : 0.f;
    float y1 = valid ? fmaxf(acc[1] + bias - LAMC, 0.f) : 0.f;
    float y2 = valid ? fmaxf(acc[2] + bias - LAMC, 0.f) : 0.f;
    float y3 = valid ? fmaxf(acc[3] + bias - LAMC, 0.f) : 0.f;
    *(uint2*)(Y + d * 32 + mside * 16 + ((l >> 4) << 2)) =
        make_uint2(pack2(y0, y1), pack2(y2, y3));
  }
  __syncthreads();

  // P7b: u += CS_i @ Y_i ; store u bf16 (kappa = d*8 + k2 order)
  {
    short8 cs1 = *(const short8*)(CSfrag + ((64 + l) << 3));
#pragma unroll
    for (int ti = 0; ti < 2; ++ti) {
      int nu = w + 6 * ti;
      if (nu < 11) {
        short8 bfr = *(const short8*)(Y + (nu * 16 + (l & 15)) * 32 + ((l >> 4) << 3));
        uacc[ti] = __builtin_amdgcn_mfma_f32_16x16x32_bf16(cs1, bfr, uacc[ti], 0, 0, 0);
        int q = l >> 4;
        int d = nu * 16 + (l & 15);
        if (q < 2 && d < MD) {
          uint2 pv = make_uint2(pack2(uacc[ti][0], uacc[ti][1]),
                                pack2(uacc[ti][2], uacc[ti][3]));
          *(uint2*)(u_out + (long)b * KD + d * 8 + q * 4) = pv;
        }
      }
    }
  }
}

// ---- Kernel 3: fused tail — root branch (MFMA + 2xLN) + conv GEMM ----
// 512 blocks x 256 thr, 16 b-rows per block.
__global__ __launch_bounds__(256) void k_tail(
    const int* __restrict__ node_ids, const float* __restrict__ t,
    const float* __restrict__ node_mem, const short* __restrict__ u,
    const short* __restrict__ convB, const float* __restrict__ conv_b,
    const short* __restrict__ Rfrag, const float* __restrict__ lin_b,
    const float* __restrict__ mb_w, const float* __restrict__ mb_b,
    const float* __restrict__ ln_w, const float* __restrict__ ln_b,
    float* __restrict__ out) {
  __shared__ __align__(16) unsigned char s_buf[11264];   // aR bf16 16x296 (9472) -> Ct f32 16x176
  __shared__ float s_fq[TD];
  short* aR = (short*)s_buf;
  float* Ct = (float*)s_buf;
  const int tid = threadIdx.x;
  const int l = tid & 63, w = tid >> 6;
  const int b0 = blockIdx.x * 16;

  if (tid < TD) s_fq[tid] = (float)exp(-9.0 * (double)tid / 99.0 * 2.302585092994045684);
  __syncthreads();

  // T1: stage A = [time_encode(t) | node_mem] bf16, 16 x 296 (cols >=272 zero)
  for (int idx = tid; idx < 16 * 296; idx += 256) {
    int r = idx / 296, c = idx - r * 296;
    float v = 0.f;
    if (c < TD) v = cosf(t[b0 + r] * s_fq[c]);
    else if (c < 272) v = node_mem[(long)node_ids[b0 + r] * MD + (c - TD)];
    aR[idx] = bf16_bits(v);
  }
  __syncthreads();

  // T2: root MFMA  rootC[16 x 176] = A @ (hw*lin_w)
  const int start = w * 3;
  const int cnt = (w < 3) ? 3 : 2;
  f32x4 racc[3];
  racc[0] = (f32x4)(0.f); racc[1] = (f32x4)(0.f); racc[2] = (f32x4)(0.f);
  {
    const short* arp = aR + (l & 15) * 296 + ((l >> 4) << 3);
    for (int s = 0; s < 9; ++s) {
      short8 a = *(const short8*)(arp + s * 32);
#pragma unroll
      for (int tt = 0; tt < 3; ++tt) {
        if (tt < cnt) {
          int n = start + tt;
          short8 bb = *(const short8*)(Rfrag + (((n * 9 + s) * 64) + l) * 8);
          racc[tt] = __builtin_amdgcn_mfma_f32_16x16x32_bf16(a, bb, racc[tt], 0, 0, 0);
        }
      }
    }
  }
  // T3: conv MFMA (validated R2/R3 structure)
  f32x4 cacc[3];
  cacc[0] = (f32x4)(0.f); cacc[1] = (f32x4)(0.f); cacc[2] = (f32x4)(0.f);
  {
    const short* ap = u + (long)(b0 + (l & 15)) * KD + ((l >> 4) << 3);
    for (int s = 0; s < 43; ++s) {
      short8 a = *(const short8*)(ap + s * 32);
#pragma unroll
      for (int tt = 0; tt < 3; ++tt) {
        if (tt < cnt) {
          long n0 = start + tt;
          short8 bb = *(const short8*)(convB + ((n0 * 43 + s) * 64 + l) * 8);
          cacc[tt] = __builtin_amdgcn_mfma_f32_16x16x32_bf16(a, bb, cacc[tt], 0, 0, 0);
        }
      }
    }
  }
  __syncthreads();

  // T4: rootC -> Ct
#pragma unroll
  for (int tt = 0; tt < 3; ++tt) {
    if (tt < cnt) {
      int n = (start + tt) * 16 + (l & 15);
      if (n < MD) {
#pragma unroll
        for (int r = 0; r < 4; ++r)
          Ct[((l >> 4) * 4 + r) * 176 + n] = racc[tt][r];
      }
    }
  }
  __syncthreads();

  // T5: two LayerNorms per row (16 lanes per row, fp32)
  {
    int r = tid >> 4, g = tid & 15;
    float v[11];
    float sm = 0.f, sq = 0.f;
#pragma unroll
    for (int j = 0; j < 11; ++j) {
      int c = g + 16 * j;
      float x = (c < MD) ? (Ct[r * 176 + c] + lin_b[c]) : 0.f;
      v[j] = x; sm += x; sq += x * x;
    }
#pragma unroll
    for (int m = 1; m < 16; m <<= 1) { sm += __shfl_xor(sm, m, 64); sq += __shfl_xor(sq, m, 64); }
    float mean = sm / 172.f;
    float rstd = rsqrtf(sq / 172.f - mean * mean + 1e-5f);
    float sm2 = 0.f, sq2 = 0.f;
#pragma unroll
    for (int j = 0; j < 11; ++j) {
      int c = g + 16 * j;
      if (c < MD) {
        float h = (v[j] - mean) * rstd * mb_w[c] + mb_b[c];
        v[j] = h; sm2 += h; sq2 += h * h;
      }
    }
#pragma unroll
    for (int m = 1; m < 16; m <<= 1) { sm2 += __shfl_xor(sm2, m, 64); sq2 += __shfl_xor(sq2, m, 64); }
    float mean2 = sm2 / 172.f;
    float rstd2 = rsqrtf(sq2 / 172.f - mean2 * mean2 + 1e-5f);
#pragma unroll
    for (int j = 0; j < 11; ++j) {
      int c = g + 16 * j;
      if (c < MD) Ct[r * 176 + c] = (v[j] - mean2) * rstd2 * ln_w[c] + ln_b[c];
    }
  }
  __syncthreads();

  // T6: out = root + conv/33 + conv_b
#pragma unroll
  for (int tt = 0; tt < 3; ++tt) {
    if (tt < cnt) {
      int n = (start + tt) * 16 + (l & 15);
      if (n < MD) {
        float cb = conv_b[n];
#pragma unroll
        for (int r = 0; r < 4; ++r) {
          int mr = (l >> 4) * 4 + r;
          out[(long)(b0 + mr) * MD + n] =
              Ct[mr * 176 + n] + cacc[tt][r] * (1.0f / 33.0f) + cb;
        }
      }
    }
  }
}

extern "C" void kernel_launch(void* const* d_in, const int* in_sizes, int n_in,
                              void* d_out, int out_size, void* d_ws, size_t ws_size,
                              hipStream_t stream) {
  const int* node_ids = (const int*)d_in[0];
  const int* nbr_id   = (const int*)d_in[1];
  const float* t  = (const float*)d_in[2];
  const float* nt = (const float*)d_in[3];
  const float* node_mem = (const float*)d_in[4];
  const float* r1 = (const float*)d_in[5];
  const float* i1 = (const float*)d_in[6];
  const float* rb1 = (const float*)d_in[7];
  const float* ib1 = (const float*)d_in[8];
  const float* conv_w = (const float*)d_in[9];
  const float* conv_b = (const float*)d_in[10];
  const float* rhythm_w = (const float*)d_in[11];
  const float* lin_w = (const float*)d_in[12];
  const float* lin_b = (const float*)d_in[13];
  const float* mb_w = (const float*)d_in[14];
  const float* mb_b = (const float*)d_in[15];
  const float* ln_w = (const float*)d_in[16];
  const float* ln_b = (const float*)d_in[17];
  float* out = (float*)d_out;
  float* wsf = (float*)d_ws;

  char* base = (char*)d_ws;
  short* u      = (short*)(base + WS_U_OFF);
  short* convB  = (short*)(base + WS_U_OFF + U_BYTES);
  short* Wfrag  = convB + CONVB_ELEMS;
  short* CSfrag = Wfrag + WBIG_ELEMS;
  short* Rfrag  = CSfrag + CS_ELEMS;

  hipMemsetAsync(d_ws, 0, 16, stream);
  k_mean<<<1024, 256, 0, stream>>>(nbr_id, t, nt, wsf);
  k_prep<<<(CONVB_ELEMS + 255) / 256, 256, 0, stream>>>(conv_w, convB);
  k_prep3<<<(WBIG_ELEMS + CS_ELEMS + ROOT_ELEMS + 255) / 256, 256, 0, stream>>>(
      r1, i1, rhythm_w, lin_w, Wfrag, CSfrag, Rfrag);
  k_main<<<B_, 384, 0, stream>>>(nbr_id, t, nt, rb1, ib1, wsf, Wfrag, CSfrag, u);
  k_tail<<<512, 256, 0, stream>>>(node_ids, t, node_mem, u, convB, conv_b,
                                  Rfrag, lin_b, mb_w, mb_b, ln_w, ln_b, out);
}

// Round 5
// 615.399 us; speedup vs baseline: 2.5530x; 1.0598x over previous
//
#include <hip/hip_runtime.h>
#include <hip/hip_bf16.h>
#include <math.h>

#define B_ 8192
#define NN 32
#define TD 100
#define MD 172
#define KD 1376   // MD*8
#define TAUC 0.3f
#define LAMC 0.01f

typedef __attribute__((ext_vector_type(8))) short short8;
typedef __attribute__((ext_vector_type(4))) float f32x4;

// ws layout (need ~23.3MB; ws_size ~1.37GB evidenced by harness poison fill)
#define WS_U_OFF    256
#define U_BYTES     ((size_t)B_ * KD * 2)
#define CONVB_ELEMS (11 * 43 * 64 * 8)     // 242688
#define WBIG_ELEMS  (22 * 7 * 64 * 8)      // 78848
#define CS_ELEMS    (2 * 64 * 8)           // 1024
#define ROOT_ELEMS  (11 * 9 * 64 * 8)      // 50688
#define FRAG_SHORTS (CONVB_ELEMS + WBIG_ELEMS + CS_ELEMS + ROOT_ELEMS)
#define TBL_ELEMS   164                    // fr[100] c32[32] s32[32]

__device__ __forceinline__ float wred(float v) {
#pragma unroll
  for (int o = 32; o > 0; o >>= 1) v += __shfl_down(v, o, 64);
  return v;
}

__device__ __forceinline__ short bf16_bits(float f) {
  __hip_bfloat16 h = __float2bfloat16(f);
  return *(short*)&h;
}

__device__ __forceinline__ unsigned pack2(float a, float b) {
  return (unsigned)(unsigned short)bf16_bits(a) |
         ((unsigned)(unsigned short)bf16_bits(b) << 16);
}

// fast cos: cos(x) via revolutions + v_cos_f32. |err| <= ~6e-5 for |x|<=1000.
__device__ __forceinline__ float fcos(float x) {
  float r = x * 0.15915494309189535f;
  r = r - floorf(r);
  return __builtin_amdgcn_cosf(r);
}

// ---- Kernel 0: all weight-fragment tables + fr/c32/s32 ----
__global__ __launch_bounds__(256) void k_prep0(
    const float* __restrict__ conv_w, const float* __restrict__ r1,
    const float* __restrict__ i1, const float* __restrict__ rhythm_w,
    const float* __restrict__ lin_w, short* __restrict__ convB,
    short* __restrict__ Wfrag, short* __restrict__ CSfrag,
    short* __restrict__ Rfrag, float* __restrict__ tbl) {
  int idx = blockIdx.x * 256 + threadIdx.x;
  const float inv_s = 0.17677669529663687f;
  if (idx < CONVB_ELEMS) {
    int j = idx & 7;
    int l = (idx >> 3) & 63;
    int s = (idx >> 9) % 43;
    int n0 = idx / (43 * 64 * 8);
    int k = s * 32 + (l >> 4) * 8 + j;
    int col = n0 * 16 + (l & 15);
    float v = (col < MD) ? conv_w[(long)col * KD + k] : 0.f;
    convB[idx] = bf16_bits(v);
    return;
  }
  idx -= CONVB_ELEMS;
  if (idx < WBIG_ELEMS) {
    int j = idx & 7;
    int l = (idx >> 3) & 63;
    int s = (idx % 3584) >> 9;
    int n0 = idx / 3584;
    int k = s * 32 + (l >> 4) * 8 + j;
    int col = n0 * 16 + (l & 15);
    float v = 0.f;
    if (k < 200) {
      if (n0 < 11) {
        int d = col;
        if (d < MD) v = (k < 100) ? r1[k * MD + d] : -i1[(k - 100) * MD + d];
      } else {
        int d = col - 176;
        if (d >= 0 && d < MD) v = (k < 100) ? i1[k * MD + d] : r1[(k - 100) * MD + d];
      }
    }
    Wfrag[idx] = bf16_bits(v);
    return;
  }
  idx -= WBIG_ELEMS;
  if (idx < CS_ELEMS) {
    int j = idx & 7;
    int l = (idx >> 3) & 63;
    int s = idx >> 9;
    int row = l & 15;
    int kq = s * 32 + (l >> 4) * 8 + j;
    float v = 0.f;
    if (row < 8) {
      int kp = (kq < 32) ? kq : kq - 32;
      int lo = row - 4; if (lo < 0) lo = 0;
      int hi = row + 28; if (hi > 31) hi = 31;
      double cs = 0.0, ss = 0.0;
      for (int n = lo; n <= hi; ++n) {
        double ang = 0.19634954084936207740 * (double)((kp * n) & 31);
        cs += cos(ang); ss += sin(ang);
      }
      v = ((kq < 32) ? (float)cs : -(float)ss) * inv_s;
    }
    CSfrag[idx] = bf16_bits(v);
    return;
  }
  idx -= CS_ELEMS;
  if (idx < ROOT_ELEMS) {
    int n = idx / 4608;
    int rem = idx % 4608;
    int s = rem >> 9;
    int l = (rem >> 3) & 63;
    int j = rem & 7;
    int k = s * 32 + (l >> 4) * 8 + j;
    int col = n * 16 + (l & 15);
    float v = 0.f;
    if (k < 272 && col < MD) {
      float hw = 0.5f * (rhythm_w[k * 4 + 1] + rhythm_w[k * 4 + 2]);
      v = hw * lin_w[k * MD + col];
    }
    Rfrag[idx] = bf16_bits(v);
    return;
  }
  idx -= ROOT_ELEMS;
  if (idx < TBL_ELEMS) {
    float v;
    if (idx < 100)      v = (float)exp(-9.0 * (double)idx / 99.0 * 2.302585092994045684);
    else if (idx < 132) v = (float)cos(0.19634954084936207740 * (double)(idx - 100));
    else                v = (float)sin(0.19634954084936207740 * (double)(idx - 132));
    tbl[idx] = v;
  }
}

// ---- Kernel 1: global energy mean via Parseval ----
__global__ __launch_bounds__(256) void k_mean(const int* __restrict__ nid,
                                              const float* __restrict__ t,
                                              const float* __restrict__ nt,
                                              const float* __restrict__ tbl,
                                              float* __restrict__ ws) {
  __shared__ float fr[TD];
  __shared__ float part[4];
  int tid = threadIdx.x;
  if (tid < TD) fr[tid] = tbl[tid];
  __syncthreads();
  int idx = blockIdx.x * 256 + tid;
  int b = idx >> 5;
  float s = 0.f;
  if (nid[idx] != 0) {
    float dt = t[b] - nt[idx];
    for (int c = 0; c < TD; ++c) { float v = fcos(dt * fr[c]); s = fmaf(v, v, s); }
  }
  s = wred(s);
  if ((tid & 63) == 0) part[tid >> 6] = s;
  __syncthreads();
  if (tid == 0) atomicAdd(ws, part[0] + part[1] + part[2] + part[3]);
}

// ---- Kernel 2: per-b neighbor pipeline (DFT -> mask -> MFMA -> u) ----
__global__ __launch_bounds__(384, 8) void k_main(
    const int* __restrict__ nbr_id, const float* __restrict__ t,
    const float* __restrict__ nt, const float* __restrict__ rb1,
    const float* __restrict__ ib1, const float* __restrict__ ws0,
    const short* __restrict__ Wfrag, const short* __restrict__ CSfrag,
    const float* __restrict__ tbl, short* __restrict__ u_out) {
  __shared__ __align__(16) short sA[32 * 232];           // masked [Xr|Xi|pad] bf16
  __shared__ __align__(16) unsigned char s_un[12800];    // tf f32 [32][100] -> Y bf16 [176][32]
  __shared__ float s_fr[TD];
  __shared__ float s_c32[32], s_s32[32], s_dt[32], s_z[32];
  __shared__ float s_energy[32];

  float* tf = (float*)s_un;
  short* Y = (short*)s_un;
  const int tid = threadIdx.x;
  const int b = blockIdx.x;
  const int l = tid & 63, w = tid >> 6;
  const float inv_s = 0.17677669529663687f;

  // P1: tables from tbl + per-b neighbor meta
  if (tid < 32) {
    s_c32[tid] = tbl[100 + tid];
    s_s32[tid] = tbl[132 + tid];
    int gi = b * NN + tid;
    int id = nbr_id[gi];
    float d = t[b] - nt[gi];
    s_z[tid]  = (id == 0) ? 0.f : 1.f;
    s_dt[tid] = (id == 0) ? 0.f : d;
    s_energy[tid] = 0.f;
  }
  if (tid < TD) s_fr[tid] = tbl[tid];
  __syncthreads();

  // P2: tfeat f32 (fast cos) + zero sA pad cols 200..231
  for (int idx = tid; idx < NN * TD; idx += 384) {
    int n = idx / TD, c = idx - n * TD;
    tf[idx] = s_z[n] * fcos(s_dt[n] * s_fr[c]);
  }
  if (tid < 256) {
    int row = tid >> 3, q = tid & 7;
    *(uint2*)(sA + row * 232 + 200 + q * 4) = make_uint2(0u, 0u);
  }
  __syncthreads();

  // P3: fp32 DFT over n (k<=16 + mirror), bf16 into sA, fp32 energy
  for (int task = tid; task < 17 * 25; task += 384) {
    int k = task / 25, c4 = (task - k * 25) * 4;
    float ar0=0,ar1=0,ar2=0,ar3=0, ai0=0,ai1=0,ai2=0,ai3=0;
    for (int n = 0; n < NN; ++n) {
      float4 a = *(const float4*)(tf + n * TD + c4);
      int j = (k * n) & 31;
      float cw = s_c32[j], sw = s_s32[j];
      ar0 = fmaf(a.x, cw, ar0); ai0 = fmaf(a.x, -sw, ai0);
      ar1 = fmaf(a.y, cw, ar1); ai1 = fmaf(a.y, -sw, ai1);
      ar2 = fmaf(a.z, cw, ar2); ai2 = fmaf(a.z, -sw, ai2);
      ar3 = fmaf(a.w, cw, ar3); ai3 = fmaf(a.w, -sw, ai3);
    }
    ar0*=inv_s; ar1*=inv_s; ar2*=inv_s; ar3*=inv_s;
    ai0*=inv_s; ai1*=inv_s; ai2*=inv_s; ai3*=inv_s;
    float e = ar0*ar0+ar1*ar1+ar2*ar2+ar3*ar3 + ai0*ai0+ai1*ai1+ai2*ai2+ai3*ai3;
    atomicAdd(&s_energy[k], e);
    uint2 vr = make_uint2(pack2(ar0, ar1), pack2(ar2, ar3));
    uint2 vi = make_uint2(pack2(ai0, ai1), pack2(ai2, ai3));
    *(uint2*)(sA + k * 232 + c4) = vr;
    *(uint2*)(sA + k * 232 + 100 + c4) = vi;
    if (k >= 1 && k <= 15) {
      uint2 vin = make_uint2(pack2(-ai0, -ai1), pack2(-ai2, -ai3));
      *(uint2*)(sA + (32 - k) * 232 + c4) = vr;
      *(uint2*)(sA + (32 - k) * 232 + 100 + c4) = vin;
    }
  }
  __syncthreads();

  // P5: zero rows failing the energy threshold
  {
    float gth = TAUC * (ws0[0] * (1.0f / 262144.0f) + 1e-6f);
    for (int idx = tid; idx < 800; idx += 384) {
      int row = idx / 25, q = idx - row * 25;
      int ks = (row <= 16) ? row : 32 - row;
      if (s_energy[ks] < gth)
        *(uint4*)((char*)sA + row * 464 + q * 16) = make_uint4(0u,0u,0u,0u);
    }
  }
  __syncthreads();

  // P6a: side 0 (O_r)
  const int mside = (w >= 3) ? 1 : 0;
  const int wn = w % 3;
  short8 afrag[7];
  {
    const short* ab = sA + (mside * 16 + (l & 15)) * 232 + ((l >> 4) << 3);
#pragma unroll
    for (int s = 0; s < 7; ++s) afrag[s] = *(const short8*)(ab + s * 32);
  }
  for (int n = wn; n < 11; n += 3) {
    f32x4 acc = (f32x4)(0.f);
#pragma unroll
    for (int s = 0; s < 7; ++s) {
      short8 bb = *(const short8*)(Wfrag + (((n * 7 + s) * 64) + l) * 8);
      acc = __builtin_amdgcn_mfma_f32_16x16x32_bf16(afrag[s], bb, acc, 0, 0, 0);
    }
    int d = n * 16 + (l & 15);
    bool valid = (d < MD);
    float bias = valid ? rb1[d] : 0.f;
    float y0 = valid ? fmaxf(acc[0] + bias - LAMC, 0.f) : 0.f;
    float y1 = valid ? fmaxf(acc[1] + bias - LAMC, 0.f) : 0.f;
    float y2 = valid ? fmaxf(acc[2] + bias - LAMC, 0.f) : 0.f;
    float y3 = valid ? fmaxf(acc[3] + bias - LAMC, 0.f) : 0.f;
    *(uint2*)(Y + d * 32 + mside * 16 + ((l >> 4) << 2)) =
        make_uint2(pack2(y0, y1), pack2(y2, y3));
  }
  __syncthreads();

  // P7a: u partial = CS_r @ Y_r
  f32x4 uacc[2];
  uacc[0] = (f32x4)(0.f); uacc[1] = (f32x4)(0.f);
  {
    short8 cs0 = *(const short8*)(CSfrag + (l << 3));
#pragma unroll
    for (int ti = 0; ti < 2; ++ti) {
      int nu = w + 6 * ti;
      if (nu < 11) {
        short8 bfr = *(const short8*)(Y + (nu * 16 + (l & 15)) * 32 + ((l >> 4) << 3));
        uacc[ti] = __builtin_amdgcn_mfma_f32_16x16x32_bf16(cs0, bfr, uacc[ti], 0, 0, 0);
      }
    }
  }
  __syncthreads();

  // P6b: side 1 (O_i) overwrites Y
  for (int n = wn; n < 11; n += 3) {
    f32x4 acc = (f32x4)(0.f);
    int nw = n + 11;
#pragma unroll
    for (int s = 0; s < 7; ++s) {
      short8 bb = *(const short8*)(Wfrag + (((nw * 7 + s) * 64) + l) * 8);
      acc = __builtin_amdgcn_mfma_f32_16x16x32_bf16(afrag[s], bb, acc, 0, 0, 0);
    }
    int d = n * 16 + (l & 15);
    bool valid = (d < MD);
    float bias = valid ? ib1[d] : 0.f;
    float y0 = valid ? fmaxf(acc[0] + bias - LAMC, 0.f) : 0.f;
    float y1 = valid ? fmaxf(acc[1] + bias - LAMC, 0.f) : 0.f;
    float y2 = valid ? fmaxf(acc[2] + bias - LAMC, 0.f) : 0.f;
    float y3 = valid ? fmaxf(acc[3] + bias - LAMC, 0.f) : 0.f;
    *(uint2*)(Y + d * 32 + mside * 16 + ((l >> 4) << 2)) =
        make_uint2(pack2(y0, y1), pack2(y2, y3));
  }
  __syncthreads();

  // P7b: u += CS_i @ Y_i ; store u bf16 (kappa = d*8 + k2)
  {
    short8 cs1 = *(const short8*)(CSfrag + ((64 + l) << 3));
#pragma unroll
    for (int ti = 0; ti < 2; ++ti) {
      int nu = w + 6 * ti;
      if (nu < 11) {
        short8 bfr = *(const short8*)(Y + (nu * 16 + (l & 15)) * 32 + ((l >> 4) << 3));
        uacc[ti] = __builtin_amdgcn_mfma_f32_16x16x32_bf16(cs1, bfr, uacc[ti], 0, 0, 0);
        int q = l >> 4;
        int d = nu * 16 + (l & 15);
        if (q < 2 && d < MD) {
          uint2 pv = make_uint2(pack2(uacc[ti][0], uacc[ti][1]),
                                pack2(uacc[ti][2], uacc[ti][3]));
          *(uint2*)(u_out + (long)b * KD + d * 8 + q * 4) = pv;
        }
      }
    }
  }
}

// ---- Kernel 3: fused tail, wave-specialized (conv || root), 512 thr ----
// waves 0-4: conv tiles {2w,2w+1}; wave 5: conv {10} + root {0,1,2};
// wave 6: root {3..6}; wave 7: root {7..10}. LN by tid<256. out by conv owners.
__global__ __launch_bounds__(512) void k_tail(
    const int* __restrict__ node_ids, const float* __restrict__ t,
    const float* __restrict__ node_mem, const short* __restrict__ u,
    const short* __restrict__ convB, const float* __restrict__ conv_b,
    const short* __restrict__ Rfrag, const float* __restrict__ lin_b,
    const float* __restrict__ mb_w, const float* __restrict__ mb_b,
    const float* __restrict__ ln_w, const float* __restrict__ ln_b,
    const float* __restrict__ tbl, float* __restrict__ out) {
  __shared__ __align__(16) short aR[16 * 296];     // A = [time_enc | mem | 0] bf16
  __shared__ __align__(16) float Ct[16 * 176];     // root C, then LN'd root
  const int tid = threadIdx.x;
  const int l = tid & 63, w = tid >> 6;
  const int b0 = blockIdx.x * 16;

  // T1: stage A (fast cos; fr direct from tbl, L2-hot)
  for (int idx = tid; idx < 16 * 296; idx += 512) {
    int r = idx / 296, c = idx - r * 296;
    float v = 0.f;
    if (c < TD) v = fcos(t[b0 + r] * tbl[c]);
    else if (c < 272) v = node_mem[(long)node_ids[b0 + r] * MD + (c - TD)];
    aR[idx] = bf16_bits(v);
  }
  __syncthreads();

  // conv stream (waves 0-5)
  const int cstart = (w < 5) ? w * 2 : 10;
  const int ccnt = (w < 5) ? 2 : ((w == 5) ? 1 : 0);
  f32x4 cacc[2];
  cacc[0] = (f32x4)(0.f); cacc[1] = (f32x4)(0.f);
  if (ccnt) {
    const short* ap = u + (long)(b0 + (l & 15)) * KD + ((l >> 4) << 3);
    for (int s = 0; s < 43; ++s) {
      short8 a = *(const short8*)(ap + s * 32);
#pragma unroll
      for (int tt = 0; tt < 2; ++tt) {
        if (tt < ccnt) {
          long n0 = cstart + tt;
          short8 bb = *(const short8*)(convB + ((n0 * 43 + s) * 64 + l) * 8);
          cacc[tt] = __builtin_amdgcn_mfma_f32_16x16x32_bf16(a, bb, cacc[tt], 0, 0, 0);
        }
      }
    }
  }

  // root stream (waves 5-7) -> raw root into Ct
  const int rstart = (w == 5) ? 0 : ((w == 6) ? 3 : 7);
  const int rcnt = (w == 5) ? 3 : ((w >= 6) ? 4 : 0);
  if (rcnt) {
    f32x4 racc[4];
#pragma unroll
    for (int tt = 0; tt < 4; ++tt) racc[tt] = (f32x4)(0.f);
    const short* arp = aR + (l & 15) * 296 + ((l >> 4) << 3);
    for (int s = 0; s < 9; ++s) {
      short8 a = *(const short8*)(arp + s * 32);
#pragma unroll
      for (int tt = 0; tt < 4; ++tt) {
        if (tt < rcnt) {
          int n = rstart + tt;
          short8 bb = *(const short8*)(Rfrag + (((n * 9 + s) * 64) + l) * 8);
          racc[tt] = __builtin_amdgcn_mfma_f32_16x16x32_bf16(a, bb, racc[tt], 0, 0, 0);
        }
      }
    }
#pragma unroll
    for (int tt = 0; tt < 4; ++tt) {
      if (tt < rcnt) {
        int n = (rstart + tt) * 16 + (l & 15);
        if (n < MD) {
#pragma unroll
          for (int r = 0; r < 4; ++r)
            Ct[((l >> 4) * 4 + r) * 176 + n] = racc[tt][r];
        }
      }
    }
  }
  __syncthreads();

  // LN x2 per row (tid<256: 16 rows x 16 lanes, fp32)
  if (tid < 256) {
    int r = tid >> 4, g = tid & 15;
    float v[11];
    float sm = 0.f, sq = 0.f;
#pragma unroll
    for (int j = 0; j < 11; ++j) {
      int c = g + 16 * j;
      float x = (c < MD) ? (Ct[r * 176 + c] + lin_b[c]) : 0.f;
      v[j] = x; sm += x; sq += x * x;
    }
#pragma unroll
    for (int m = 1; m < 16; m <<= 1) { sm += __shfl_xor(sm, m, 64); sq += __shfl_xor(sq, m, 64); }
    float mean = sm / 172.f;
    float rstd = rsqrtf(sq / 172.f - mean * mean + 1e-5f);
    float sm2 = 0.f, sq2 = 0.f;
#pragma unroll
    for (int j = 0; j < 11; ++j) {
      int c = g + 16 * j;
      if (c < MD) {
        float h = (v[j] - mean) * rstd * mb_w[c] + mb_b[c];
        v[j] = h; sm2 += h; sq2 += h * h;
      }
    }
#pragma unroll
    for (int m = 1; m < 16; m <<= 1) { sm2 += __shfl_xor(sm2, m, 64); sq2 += __shfl_xor(sq2, m, 64); }
    float mean2 = sm2 / 172.f;
    float rstd2 = rsqrtf(sq2 / 172.f - mean2 * mean2 + 1e-5f);
#pragma unroll
    for (int j = 0; j < 11; ++j) {
      int c = g + 16 * j;
      if (c < MD) Ct[r * 176 + c] = (v[j] - mean2) * rstd2 * ln_w[c] + ln_b[c];
    }
  }
  __syncthreads();

  // final write by conv owners: out = LN(root) + conv/33 + conv_b
#pragma unroll
  for (int tt = 0; tt < 2; ++tt) {
    if (tt < ccnt) {
      int n = (cstart + tt) * 16 + (l & 15);
      if (n < MD) {
        float cb = conv_b[n];
#pragma unroll
        for (int r = 0; r < 4; ++r) {
          int mr = (l >> 4) * 4 + r;
          out[(long)(b0 + mr) * MD + n] =
              Ct[mr * 176 + n] + cacc[tt][r] * (1.0f / 33.0f) + cb;
        }
      }
    }
  }
}

extern "C" void kernel_launch(void* const* d_in, const int* in_sizes, int n_in,
                              void* d_out, int out_size, void* d_ws, size_t ws_size,
                              hipStream_t stream) {
  const int* node_ids = (const int*)d_in[0];
  const int* nbr_id   = (const int*)d_in[1];
  const float* t  = (const float*)d_in[2];
  const float* nt = (const float*)d_in[3];
  const float* node_mem = (const float*)d_in[4];
  const float* r1 = (const float*)d_in[5];
  const float* i1 = (const float*)d_in[6];
  const float* rb1 = (const float*)d_in[7];
  const float* ib1 = (const float*)d_in[8];
  const float* conv_w = (const float*)d_in[9];
  const float* conv_b = (const float*)d_in[10];
  const float* rhythm_w = (const float*)d_in[11];
  const float* lin_w = (const float*)d_in[12];
  const float* lin_b = (const float*)d_in[13];
  const float* mb_w = (const float*)d_in[14];
  const float* mb_b = (const float*)d_in[15];
  const float* ln_w = (const float*)d_in[16];
  const float* ln_b = (const float*)d_in[17];
  float* out = (float*)d_out;
  float* wsf = (float*)d_ws;

  char* base = (char*)d_ws;
  short* u      = (short*)(base + WS_U_OFF);
  short* convB  = (short*)(base + WS_U_OFF + U_BYTES);
  short* Wfrag  = convB + CONVB_ELEMS;
  short* CSfrag = Wfrag + WBIG_ELEMS;
  short* Rfrag  = CSfrag + CS_ELEMS;
  float* tbl    = (float*)(Rfrag + ROOT_ELEMS);

  hipMemsetAsync(d_ws, 0, 16, stream);
  k_prep0<<<(FRAG_SHORTS + TBL_ELEMS + 255) / 256, 256, 0, stream>>>(
      conv_w, r1, i1, rhythm_w, lin_w, convB, Wfrag, CSfrag, Rfrag, tbl);
  k_mean<<<1024, 256, 0, stream>>>(nbr_id, t, nt, tbl, wsf);
  k_main<<<B_, 384, 0, stream>>>(nbr_id, t, nt, rb1, ib1, wsf, Wfrag, CSfrag, tbl, u);
  k_tail<<<512, 512, 0, stream>>>(node_ids, t, node_mem, u, convB, conv_b,
                                  Rfrag, lin_b, mb_w, mb_b, ln_w, ln_b, tbl, out);
}